// Round 11
// baseline (188.643 us; speedup 1.0000x reference)
//
#include <hip/hip_runtime.h>
#include <hip/hip_bf16.h>
#include <cstdint>

typedef unsigned short u16;
typedef __attribute__((ext_vector_type(8))) short short8;   // 8 x bf16 fragment
typedef __attribute__((ext_vector_type(4))) float f32x4;

__device__ __forceinline__ u16 f2bf(float f) {
  union { float f; uint32_t u; } c; c.f = f;
  return (u16)((c.u + 0x7FFFu + ((c.u >> 16) & 1u)) >> 16);
}

__device__ __forceinline__ uint32_t pack_bf16x2(float a, float b) {
  union { __hip_bfloat162 h; uint32_t u; } c;
  c.h = __float22bfloat162_rn(make_float2(a, b));   // v_cvt_pk_bf16_f32
  return c.u;
}

// ---------- fp32 -> bf16 elementwise (4 per thread) ----------
__global__ __launch_bounds__(256) void conv_bf16(const float* __restrict__ in,
                                                 u16* __restrict__ out, int n4) {
  int i = blockIdx.x * 256 + threadIdx.x;
  if (i >= n4) return;
  float4 v = ((const float4*)in)[i];
  ((ushort4*)out)[i] = make_ushort4(f2bf(v.x), f2bf(v.y), f2bf(v.z), f2bf(v.w));
}

// ---------- transpose + convert: in [K][N] f32 -> out [N][K] bf16 ----------
__global__ __launch_bounds__(256) void transpose_conv(const float* __restrict__ in,
                                                      u16* __restrict__ out, int K, int N) {
  __shared__ float tile[64][65];
  int n0 = blockIdx.x * 64, k0 = blockIdx.y * 64;
  int t = threadIdx.x;
  int a = t & 63, b4 = t >> 6;
#pragma unroll
  for (int j = 0; j < 16; ++j) {
    int kk = j * 4 + b4;
    tile[kk][a] = in[(size_t)(k0 + kk) * N + n0 + a];
  }
  __syncthreads();
#pragma unroll
  for (int j = 0; j < 16; ++j) {
    int nn = j * 4 + b4;
    out[(size_t)(n0 + nn) * K + k0 + a] = f2bf(tile[a][nn]);
  }
}

// ---------- bf16 GEMM: C[M][N] (f32,+bias) = A[M][K] * Bt[N][K]^T ----------
// 64x128 tile, BK=32, 2-phase dbuf, XCD-swizzled grid.
__global__ __launch_bounds__(256, 4) void gemm_bt(const u16* __restrict__ A,
                                                  const u16* __restrict__ Bt,
                                                  float* __restrict__ C,
                                                  const float* __restrict__ bias,
                                                  int M, int N, int K) {
  __shared__ alignas(16) u16 As[2][64 * 32];
  __shared__ alignas(16) u16 Bs[2][128 * 32];
  int nb = N >> 7;
  int nwg = gridDim.x;
  int cpx = nwg >> 3;
  int bid = blockIdx.x;
  int swz = (bid & 7) * cpx + (bid >> 3);
  int m0 = (swz / nb) << 6;
  int n0 = (swz % nb) << 7;
  int tid = threadIdx.x;
  int w = tid >> 6, lane = tid & 63;
  int wr = w >> 1, wc = w & 1;
  int fr = lane & 15, hi = lane >> 4, fk = hi * 8;
  int r0 = tid >> 2, c0 = tid & 3;

  auto STAGE = [&](int buf, int kt) {
    const u16* ga = A + (size_t)(m0 + r0) * K + kt + c0 * 8;
    u16* la = &As[buf][(size_t)(w * 64) * 8];   // wave-uniform base
    __builtin_amdgcn_global_load_lds((const __attribute__((address_space(1))) void*)ga,
                                     (__attribute__((address_space(3))) void*)la, 16, 0, 0);
#pragma unroll
    for (int b = 0; b < 2; ++b) {
      int r = (b << 6) + r0;
      const u16* gb = Bt + (size_t)(n0 + r) * K + kt + c0 * 8;
      u16* lb = &Bs[buf][(size_t)(b * 256 + w * 64) * 8];
      __builtin_amdgcn_global_load_lds((const __attribute__((address_space(1))) void*)gb,
                                       (__attribute__((address_space(3))) void*)lb, 16, 0, 0);
    }
  };

  f32x4 acc[2][4] = {};
  STAGE(0, 0);
  __syncthreads();
  int cur = 0;
  for (int kt = 0; kt < K; kt += 32) {
    if (kt + 32 < K) STAGE(cur ^ 1, kt + 32);
    short8 af[2], bfr[4];
#pragma unroll
    for (int m = 0; m < 2; ++m) af[m] = *(const short8*)&As[cur][(wr * 32 + m * 16 + fr) * 32 + fk];
#pragma unroll
    for (int n = 0; n < 4; ++n) bfr[n] = *(const short8*)&Bs[cur][(wc * 64 + n * 16 + fr) * 32 + fk];
#pragma unroll
    for (int m = 0; m < 2; ++m)
#pragma unroll
      for (int n = 0; n < 4; ++n)
        acc[m][n] = __builtin_amdgcn_mfma_f32_16x16x32_bf16(af[m], bfr[n], acc[m][n], 0, 0, 0);
    __syncthreads();
    cur ^= 1;
  }
#pragma unroll
  for (int m = 0; m < 2; ++m) {
#pragma unroll
    for (int n = 0; n < 4; ++n) {
      int gcol = n0 + wc * 64 + n * 16 + fr;
      float bv = bias ? bias[gcol] : 0.0f;
#pragma unroll
      for (int r = 0; r < 4; ++r) {
        int grow = m0 + wr * 32 + m * 16 + hi * 4 + r;
        C[(size_t)grow * N + gcol] = acc[m][n][r] + bv;
      }
    }
  }
}

// ---------- QKV postprocess: bias + RMSNorm + RoPE + layout [head][t][64] bf16 ----------
__global__ __launch_bounds__(256) void qkv_post(const float* __restrict__ qkv,
    const float* __restrict__ wq_b, const float* __restrict__ wk_b, const float* __restrict__ wv_b,
    const float* __restrict__ qn_w, const float* __restrict__ kn_w,
    const float* __restrict__ fc, const float* __restrict__ fs,
    u16* __restrict__ Qg, u16* __restrict__ Kg, u16* __restrict__ Vg) {
  int gid = blockIdx.x * 256 + threadIdx.x;
  int wave = gid >> 6, d = gid & 63;
  int t = wave / 48, hh = wave % 48;
  float v;
  if (hh < 32)       v = qkv[(size_t)t * 3072 + hh * 64 + d] + wq_b[hh * 64 + d];
  else if (hh < 40)  v = qkv[(size_t)t * 3072 + 2048 + (hh - 32) * 64 + d] + wk_b[(hh - 32) * 64 + d];
  else               v = qkv[(size_t)t * 3072 + 2560 + (hh - 40) * 64 + d] + wv_b[(hh - 40) * 64 + d];
  if (hh < 40) {
    float sq = v * v;
#pragma unroll
    for (int off = 32; off >= 1; off >>= 1) sq += __shfl_xor(sq, off);
    float rr = rsqrtf(sq * (1.0f / 64.0f) + 1e-5f);
    float wn = (hh < 32) ? qn_w[d] * 0.18033688f : kn_w[d];   // Q: fold 0.125*log2(e)
    v = v * rr * wn;
    float part = __shfl_xor(v, 1);
    float c = fc[t * 32 + (d >> 1)];
    float s = fs[t * 32 + (d >> 1)];
    v = (d & 1) ? (part * s + v * c) : (v * c - part * s);
  }
  u16 bv = f2bf(v);
  if (hh < 32)       Qg[((size_t)hh * 2048 + t) * 64 + d] = bv;
  else if (hh < 40)  Kg[((size_t)(hh - 32) * 2048 + t) * 64 + d] = bv;
  else               Vg[((size_t)(hh - 40) * 2048 + t) * 64 + d] = bv;
}

// ---------- causal GQA flash attention (v7: KVBLK=128, K via gload_lds, lsum-MFMA) ----------
__global__ __launch_bounds__(256, 2) void attn_kernel(const u16* __restrict__ Qg,
                                                      const u16* __restrict__ Kg,
                                                      const u16* __restrict__ Vg,
                                                      const float* __restrict__ qn_w,
                                                      const float* __restrict__ kn_w,
                                                      u16* __restrict__ att) {
  __shared__ alignas(16) u16 Ks[2][128 * 64];        // [key][d], src-swizzled via gload_lds
  __shared__ alignas(16) u16 Vs[64 * 128];           // [d][key], XOR-swizzled rows (256B)
  __shared__ alignas(16) uint32_t Ps[4][16 * 68];    // per-wave P: [q=fr][key-pair], stride 68
  char* VsB = (char*)Vs;

  // balanced remap: per-CU round-robin set {q0,15-q0,16+q0,31-q0}: nkt sums uniform (34)
  int bid = blockIdx.x;
  int grp = bid >> 8, idx = bid & 255;
  int q0 = idx >> 5, h = idx & 31;
  int qt = (grp == 0) ? q0 : (grp == 1) ? 15 - q0 : (grp == 2) ? 16 + q0 : 31 - q0;
  int kvh = h >> 2;
  int nkt = (qt >> 1) + 1;

  int tid = threadIdx.x, w = tid >> 6, lane = tid & 63;
  int fr = lane & 15, hi = lane >> 4, fk = hi * 8;

  // softmax upper bound: S_log2 <= 11.5416 * max|qn| * max|kn|
  float ba = fabsf(qn_w[lane]), bb = fabsf(kn_w[lane]);
#pragma unroll
  for (int off = 32; off >= 1; off >>= 1) {
    ba = fmaxf(ba, __shfl_xor(ba, off));
    bb = fmaxf(bb, __shfl_xor(bb, off));
  }
  float mfix = 11.5416222f * ba * bb;

  const u16* qbase = Qg + ((size_t)h * 2048 + qt * 64 + w * 16 + fr) * 64;
  short8 qf0 = *(const short8*)(qbase + fk);
  short8 qf1 = *(const short8*)(qbase + 32 + fk);
  short8 ones;
#pragma unroll
  for (int j = 0; j < 8; ++j) ones[j] = (short)0x3F80;   // bf16 1.0

  f32x4 o[4] = {};
  f32x4 o_l = {};   // row-sums of P via ones-MFMA: o_l[r] = l[q-row hi*4+r]

  const u16* Kbase = Kg + (size_t)kvh * 2048 * 64;
  const u16* Vbase = Vg + (size_t)kvh * 2048 * 64;

  // K staging: 1024 chunks of 16B; 4 issues/thread; source pre-swizzled (c ^= key&7)
  auto stage_K = [&](int buf, int kt) {
    const char* kb = (const char*)(Kbase + (size_t)kt * 128 * 64);
#pragma unroll
    for (int i = 0; i < 4; ++i) {
      int chunk = i * 256 + tid;
      int key = chunk >> 3, c = chunk & 7;
      const char* src = kb + key * 128 + ((c ^ (key & 7)) << 4);
      u16* dst = &Ks[buf][(size_t)(i * 256 + w * 64) * 8];   // wave-uniform base
      __builtin_amdgcn_global_load_lds((const __attribute__((address_space(1))) void*)src,
                                       (__attribute__((address_space(3))) void*)dst, 16, 0, 0);
    }
  };

  // V staging: thread = (kp = tid&63 -> keys 2kp,2kp+1; dg = tid>>6 -> d groups dg*8, dg*8+32)
  int kp = tid & 63, dg = tid >> 6;
  auto load_V = [&](int kt, short8& v0, short8& v1, short8& v2, short8& v3) {
    const u16* vb = Vbase + (size_t)kt * 128 * 64 + (size_t)(2 * kp) * 64 + dg * 8;
    v0 = *(const short8*)vb;
    v1 = *(const short8*)(vb + 64);
    v2 = *(const short8*)(vb + 32);
    v3 = *(const short8*)(vb + 96);
  };
  auto write_V = [&](short8 v0, short8 v1, short8 v2, short8 v3) {
#pragma unroll
    for (int j = 0; j < 8; ++j) {
      int d = dg * 8 + j;
      uint32_t pk = (uint32_t)(u16)v0[j] | ((uint32_t)(u16)v1[j] << 16);
      *(uint32_t*)(VsB + ((d * 256 + kp * 4) ^ ((d & 15) << 4))) = pk;
      int d2 = d + 32;
      uint32_t pk2 = (uint32_t)(u16)v2[j] | ((uint32_t)(u16)v3[j] << 16);
      *(uint32_t*)(VsB + ((d2 * 256 + kp * 4) ^ ((d2 & 15) << 4))) = pk2;
    }
  };

  short8 vA0, vA1, vA2, vA3, vB0, vB1, vB2, vB3;
  stage_K(0, 0);
  load_V(0, vA0, vA1, vA2, vA3);

  uint32_t* Pw = &Ps[w][0];
  int qrow = qt * 64 + w * 16 + fr;
  int kbuf = 0;

  for (int kt = 0; kt < nkt; ++kt) {
    bool last = (kt == nkt - 1);
    if ((kt & 1) == 0) write_V(vA0, vA1, vA2, vA3);
    else               write_V(vB0, vB1, vB2, vB3);
    __syncthreads();   // drains K gload(kt) + V ds_writes
    if (!last) {
      stage_K(kbuf ^ 1, kt + 1);   // hidden under QK+softmax+PV
      if ((kt & 1) == 0) load_V(kt + 1, vB0, vB1, vB2, vB3);
      else               load_V(kt + 1, vA0, vA1, vA2, vA3);
    }
    // S^T = K Q^T (log2 units): s4[g], keys g*16+hi*4+r, q-row fr
    const char* KsB = (const char*)&Ks[kbuf][0];
    f32x4 s4[8] = {};
    __builtin_amdgcn_s_setprio(1);
#pragma unroll
    for (int g = 0; g < 8; ++g) {
      int rk = g * 16 + fr;
      int rb = rk * 128;
      int sw7 = rk & 7;
      short8 b0 = *(const short8*)(KsB + rb + ((hi ^ sw7) << 4));
      short8 b1 = *(const short8*)(KsB + rb + (((4 + hi) ^ sw7) << 4));
      s4[g] = __builtin_amdgcn_mfma_f32_16x16x32_bf16(b0, qf0, s4[g], 0, 0, 0);
      s4[g] = __builtin_amdgcn_mfma_f32_16x16x32_bf16(b1, qf1, s4[g], 0, 0, 0);
    }
    __builtin_amdgcn_s_setprio(0);
    if (last) {   // causal mask only on the final (diagonal) K-tile
      int kb0 = kt * 128 + hi * 4;
#pragma unroll
      for (int g = 0; g < 8; ++g)
#pragma unroll
        for (int r = 0; r < 4; ++r)
          if (kb0 + g * 16 + r > qrow) s4[g][r] = -1e30f;
    }
    // P = exp2(S - mfix); cvt_pk pack; write to Ps
#pragma unroll
    for (int g = 0; g < 8; ++g) {
      float p0 = exp2f(s4[g][0] - mfix);
      float p1 = exp2f(s4[g][1] - mfix);
      float p2 = exp2f(s4[g][2] - mfix);
      float p3 = exp2f(s4[g][3] - mfix);
      uint2 pk = make_uint2(pack_bf16x2(p0, p1), pack_bf16x2(p2, p3));
      *(uint2*)&Pw[fr * 68 + g * 8 + hi * 2] = pk;
    }
    asm volatile("s_waitcnt lgkmcnt(0)" ::: "memory");  // P writes land (wave-local)
    short8 pa[4];
#pragma unroll
    for (int j = 0; j < 4; ++j)
      pa[j] = *(const short8*)&Pw[fr * 68 + j * 16 + hi * 4];
    __builtin_amdgcn_s_setprio(1);
#pragma unroll
    for (int j = 0; j < 4; ++j)   // l-sums on the MFMA pipe
      o_l = __builtin_amdgcn_mfma_f32_16x16x32_bf16(pa[j], ones, o_l, 0, 0, 0);
#pragma unroll
    for (int g2 = 0; g2 < 4; ++g2) {
      int rd = g2 * 16 + fr;
      int rb = rd * 256;
      int sw = (rd & 15) << 4;
#pragma unroll
      for (int j = 0; j < 4; ++j) {
        short8 vbf = *(const short8*)(VsB + rb + (((j * 64 + hi * 16)) ^ sw));
        o[g2] = __builtin_amdgcn_mfma_f32_16x16x32_bf16(pa[j], vbf, o[g2], 0, 0, 0);
      }
    }
    __builtin_amdgcn_s_setprio(0);
    __syncthreads();
    kbuf ^= 1;
  }
#pragma unroll
  for (int r = 0; r < 4; ++r) {
    float inv = 1.0f / o_l[r];
    size_t rowoff = (size_t)(qt * 64 + w * 16 + hi * 4 + r) * 2048 + h * 64;
#pragma unroll
    for (int g2 = 0; g2 < 4; ++g2)
      att[rowoff + g2 * 16 + fr] = f2bf(o[g2][r] * inv);
  }
}

extern "C" void kernel_launch(void* const* d_in, const int* in_sizes, int n_in,
                              void* d_out, int out_size, void* d_ws, size_t ws_size,
                              hipStream_t stream) {
  const float* x    = (const float*)d_in[0];
  const float* fc   = (const float*)d_in[1];
  const float* fs   = (const float*)d_in[2];
  // d_in[3] = mask (causal, regenerated in-kernel)
  const float* wq   = (const float*)d_in[4];
  const float* wq_b = (const float*)d_in[5];
  const float* wk   = (const float*)d_in[6];
  const float* wk_b = (const float*)d_in[7];
  const float* wv   = (const float*)d_in[8];
  const float* wv_b = (const float*)d_in[9];
  const float* wo   = (const float*)d_in[10];
  const float* wo_b = (const float*)d_in[11];
  const float* qn   = (const float*)d_in[12];
  const float* kn   = (const float*)d_in[13];
  float* out = (float*)d_out;

  char* ws = (char*)d_ws;
  u16*  xb    = (u16*)(ws);                          //  8 MB  x bf16 [2048][2048]
  u16*  wqkvT = (u16*)(ws + (size_t)(8  << 20));     // 12 MB  [3072][2048] bf16
  u16*  woT   = (u16*)(ws + (size_t)(20 << 20));     //  8 MB  [2048][2048] bf16
  float* qkv  = (float*)(ws + (size_t)(28 << 20));   // 24 MB  [2048][3072] f32
  u16*  Qg    = (u16*)(ws + (size_t)(52 << 20));     //  8 MB  [32][2048][64]
  u16*  Kg    = (u16*)(ws + (size_t)(60 << 20));     //  2 MB  [8][2048][64]
  u16*  Vg    = (u16*)(ws + (size_t)(62 << 20));     //  2 MB  [8][2048][64]
  u16*  att   = (u16*)(ws + (size_t)(64 << 20));     //  8 MB  [2048][2048]

  conv_bf16<<<4096, 256, 0, stream>>>(x, xb, 1048576);
  transpose_conv<<<dim3(32, 32), 256, 0, stream>>>(wq, wqkvT, 2048, 2048);
  transpose_conv<<<dim3(8, 32),  256, 0, stream>>>(wk, wqkvT + (size_t)2048 * 2048, 2048, 512);
  transpose_conv<<<dim3(8, 32),  256, 0, stream>>>(wv, wqkvT + (size_t)2560 * 2048, 2048, 512);
  transpose_conv<<<dim3(32, 32), 256, 0, stream>>>(wo, woT, 2048, 2048);
  gemm_bt<<<32 * 24, 256, 0, stream>>>(xb, wqkvT, qkv, (const float*)nullptr, 2048, 3072, 2048);
  qkv_post<<<24576, 256, 0, stream>>>(qkv, wq_b, wk_b, wv_b, qn, kn, fc, fs, Qg, Kg, Vg);
  attn_kernel<<<1024, 256, 0, stream>>>(Qg, Kg, Vg, qn, kn, att);
  gemm_bt<<<32 * 16, 256, 0, stream>>>(att, woT, out, wo_b, 2048, 2048, 2048);
}

// Round 12
// 153.664 us; speedup vs baseline: 1.2276x; 1.2276x over previous
//
#include <hip/hip_runtime.h>
#include <hip/hip_bf16.h>
#include <cstdint>

typedef unsigned short u16;
typedef __attribute__((ext_vector_type(8))) short short8;   // 8 x bf16 fragment
typedef __attribute__((ext_vector_type(4))) float f32x4;

__device__ __forceinline__ u16 f2bf(float f) {
  union { float f; uint32_t u; } c; c.f = f;
  return (u16)((c.u + 0x7FFFu + ((c.u >> 16) & 1u)) >> 16);
}

__device__ __forceinline__ uint32_t pack_bf16x2(float a, float b) {
  union { __hip_bfloat162 h; uint32_t u; } c;
  c.h = __float22bfloat162_rn(make_float2(a, b));   // v_cvt_pk_bf16_f32
  return c.u;
}

// ---------- fp32 -> bf16 elementwise (4 per thread) ----------
__global__ __launch_bounds__(256) void conv_bf16(const float* __restrict__ in,
                                                 u16* __restrict__ out, int n4) {
  int i = blockIdx.x * 256 + threadIdx.x;
  if (i >= n4) return;
  float4 v = ((const float4*)in)[i];
  ((ushort4*)out)[i] = make_ushort4(f2bf(v.x), f2bf(v.y), f2bf(v.z), f2bf(v.w));
}

// ---------- all 4 weight transposes in one launch: [K][N] f32 -> [N][K] bf16 ----------
__global__ __launch_bounds__(256) void transpose_all(const float* __restrict__ wq,
                                                     const float* __restrict__ wk,
                                                     const float* __restrict__ wv,
                                                     const float* __restrict__ wo,
                                                     u16* __restrict__ wqkvT,
                                                     u16* __restrict__ woT) {
  __shared__ float tile[64][65];
  const int K = 2048;
  int bx = blockIdx.x;
  const float* in; u16* out; int N, nx;
  if (bx < 32)      { in = wq; out = wqkvT;                          N = 2048; nx = bx; }
  else if (bx < 40) { in = wk; out = wqkvT + (size_t)2048 * 2048;    N = 512;  nx = bx - 32; }
  else if (bx < 48) { in = wv; out = wqkvT + (size_t)2560 * 2048;    N = 512;  nx = bx - 40; }
  else              { in = wo; out = woT;                            N = 2048; nx = bx - 48; }
  int n0 = nx * 64, k0 = blockIdx.y * 64;
  int t = threadIdx.x;
  int a = t & 63, b4 = t >> 6;
#pragma unroll
  for (int j = 0; j < 16; ++j) {
    int kk = j * 4 + b4;
    tile[kk][a] = in[(size_t)(k0 + kk) * N + n0 + a];
  }
  __syncthreads();
#pragma unroll
  for (int j = 0; j < 16; ++j) {
    int nn = j * 4 + b4;
    out[(size_t)(n0 + nn) * K + k0 + a] = f2bf(tile[a][nn]);
  }
}

// ---------- bf16 GEMM: C[M][N] (f32,+bias) = A[M][K] * Bt[N][K]^T ----------
// 64x128 tile, BK=64, 2-phase dbuf, chunk-XOR swizzled LDS (pre-swizzled source,
// linear dest, swizzled read), XCD-swizzled grid.
__global__ __launch_bounds__(256, 3) void gemm_bt(const u16* __restrict__ A,
                                                  const u16* __restrict__ Bt,
                                                  float* __restrict__ C,
                                                  const float* __restrict__ bias,
                                                  int M, int N, int K) {
  __shared__ alignas(16) u16 As[2][64 * 64];     // [row][k], row chunk-swizzled
  __shared__ alignas(16) u16 Bs[2][128 * 64];
  int nb = N >> 7;
  int nwg = gridDim.x;
  int cpx = nwg >> 3;
  int bid = blockIdx.x;
  int swz = (bid & 7) * cpx + (bid >> 3);
  int m0 = (swz / nb) << 6;
  int n0 = (swz % nb) << 7;
  int tid = threadIdx.x;
  int w = tid >> 6, lane = tid & 63;
  int wr = w >> 1, wc = w & 1;
  int fr = lane & 15, hi = lane >> 4;
  int sw = fr & 7;                       // read-side swizzle (row&7 == fr&7)

  auto STAGE = [&](int buf, int kt) {
    // A: 64x64 = 512 chunks of 16B, 2/thread
#pragma unroll
    for (int i = 0; i < 2; ++i) {
      int chunk = i * 256 + tid;
      int row = chunk >> 3, c = chunk & 7;
      const u16* ga = A + (size_t)(m0 + row) * K + kt + ((c ^ (row & 7)) << 3);
      u16* la = &As[buf][(size_t)(i * 256 + w * 64) * 8];
      __builtin_amdgcn_global_load_lds((const __attribute__((address_space(1))) void*)ga,
                                       (__attribute__((address_space(3))) void*)la, 16, 0, 0);
    }
    // B: 128x64 = 1024 chunks, 4/thread
#pragma unroll
    for (int i = 0; i < 4; ++i) {
      int chunk = i * 256 + tid;
      int row = chunk >> 3, c = chunk & 7;
      const u16* gb = Bt + (size_t)(n0 + row) * K + kt + ((c ^ (row & 7)) << 3);
      u16* lb = &Bs[buf][(size_t)(i * 256 + w * 64) * 8];
      __builtin_amdgcn_global_load_lds((const __attribute__((address_space(1))) void*)gb,
                                       (__attribute__((address_space(3))) void*)lb, 16, 0, 0);
    }
  };

  f32x4 acc[2][4] = {};
  STAGE(0, 0);
  __syncthreads();
  int cur = 0;
  int c0 = (hi ^ sw) << 3, c1 = ((4 + hi) ^ sw) << 3;   // k-chunk LDS offsets (u16)
  for (int kt = 0; kt < K; kt += 64) {
    if (kt + 64 < K) STAGE(cur ^ 1, kt + 64);
    short8 af[2][2], bf[4][2];
#pragma unroll
    for (int m = 0; m < 2; ++m) {
      int rb = (wr * 32 + m * 16 + fr) * 64;
      af[m][0] = *(const short8*)&As[cur][rb + c0];
      af[m][1] = *(const short8*)&As[cur][rb + c1];
    }
#pragma unroll
    for (int n = 0; n < 4; ++n) {
      int rb = (wc * 64 + n * 16 + fr) * 64;
      bf[n][0] = *(const short8*)&Bs[cur][rb + c0];
      bf[n][1] = *(const short8*)&Bs[cur][rb + c1];
    }
#pragma unroll
    for (int m = 0; m < 2; ++m)
#pragma unroll
      for (int n = 0; n < 4; ++n) {
        acc[m][n] = __builtin_amdgcn_mfma_f32_16x16x32_bf16(af[m][0], bf[n][0], acc[m][n], 0, 0, 0);
        acc[m][n] = __builtin_amdgcn_mfma_f32_16x16x32_bf16(af[m][1], bf[n][1], acc[m][n], 0, 0, 0);
      }
    __syncthreads();
    cur ^= 1;
  }
#pragma unroll
  for (int m = 0; m < 2; ++m) {
#pragma unroll
    for (int n = 0; n < 4; ++n) {
      int gcol = n0 + wc * 64 + n * 16 + fr;
      float bv = bias ? bias[gcol] : 0.0f;
#pragma unroll
      for (int r = 0; r < 4; ++r) {
        int grow = m0 + wr * 32 + m * 16 + hi * 4 + r;
        C[(size_t)grow * N + gcol] = acc[m][n][r] + bv;
      }
    }
  }
}

// ---------- QKV postprocess: bias + RMSNorm + RoPE + layout [head][t][64] bf16 ----------
__global__ __launch_bounds__(256) void qkv_post(const float* __restrict__ qkv,
    const float* __restrict__ wq_b, const float* __restrict__ wk_b, const float* __restrict__ wv_b,
    const float* __restrict__ qn_w, const float* __restrict__ kn_w,
    const float* __restrict__ fc, const float* __restrict__ fs,
    u16* __restrict__ Qg, u16* __restrict__ Kg, u16* __restrict__ Vg) {
  int gid = blockIdx.x * 256 + threadIdx.x;
  int wave = gid >> 6, d = gid & 63;
  int t = wave / 48, hh = wave % 48;
  float v;
  if (hh < 32)       v = qkv[(size_t)t * 3072 + hh * 64 + d] + wq_b[hh * 64 + d];
  else if (hh < 40)  v = qkv[(size_t)t * 3072 + 2048 + (hh - 32) * 64 + d] + wk_b[(hh - 32) * 64 + d];
  else               v = qkv[(size_t)t * 3072 + 2560 + (hh - 40) * 64 + d] + wv_b[(hh - 40) * 64 + d];
  if (hh < 40) {
    float sq = v * v;
#pragma unroll
    for (int off = 32; off >= 1; off >>= 1) sq += __shfl_xor(sq, off);
    float rr = rsqrtf(sq * (1.0f / 64.0f) + 1e-5f);
    float wn = (hh < 32) ? qn_w[d] * 0.18033688f : kn_w[d];   // Q: fold 0.125*log2(e)
    v = v * rr * wn;
    float part = __shfl_xor(v, 1);
    float c = fc[t * 32 + (d >> 1)];
    float s = fs[t * 32 + (d >> 1)];
    v = (d & 1) ? (part * s + v * c) : (v * c - part * s);
  }
  u16 bv = f2bf(v);
  if (hh < 32)       Qg[((size_t)hh * 2048 + t) * 64 + d] = bv;
  else if (hh < 40)  Kg[((size_t)(hh - 32) * 2048 + t) * 64 + d] = bv;
  else               Vg[((size_t)(hh - 40) * 2048 + t) * 64 + d] = bv;
}

// ---------- causal GQA flash attention (v6: fixed-max, in-kernel bound) ----------
__global__ __launch_bounds__(256, 4) void attn_kernel(const u16* __restrict__ Qg,
                                                      const u16* __restrict__ Kg,
                                                      const u16* __restrict__ Vg,
                                                      const float* __restrict__ qn_w,
                                                      const float* __restrict__ kn_w,
                                                      u16* __restrict__ att) {
  __shared__ alignas(16) u16 Ks[64 * 64];            // [key][d], XOR-swizzled rows
  __shared__ alignas(16) u16 Vs[64 * 64];            // [d][key], XOR-swizzled rows
  __shared__ alignas(16) uint32_t Ps[4][16 * 36];    // per-wave P: [q=fr][key-pair], stride 36
  char* KsB = (char*)Ks;
  char* VsB = (char*)Vs;

  // balanced remap: each CU's round-robin set {q0,15-q0,16+q0,31-q0} sums uniform
  int bid = blockIdx.x;
  int grp = bid >> 8, idx = bid & 255;
  int q0 = idx >> 5, h = idx & 31;
  int qt = (grp == 0) ? q0 : (grp == 1) ? 15 - q0 : (grp == 2) ? 16 + q0 : 31 - q0;
  int kvh = h >> 2;

  int tid = threadIdx.x, w = tid >> 6, lane = tid & 63;
  int fr = lane & 15, hi = lane >> 4, fk = hi * 8;

  // softmax upper bound: S_log2 <= 11.5416 * max|qn| * max|kn|
  float ba = fabsf(qn_w[lane]), bb = fabsf(kn_w[lane]);
#pragma unroll
  for (int off = 32; off >= 1; off >>= 1) {
    ba = fmaxf(ba, __shfl_xor(ba, off));
    bb = fmaxf(bb, __shfl_xor(bb, off));
  }
  float mfix = 11.5416222f * ba * bb;   // uniform softmax max (log2 domain)

  const u16* qbase = Qg + ((size_t)h * 2048 + qt * 64 + w * 16 + fr) * 64;
  short8 qf0 = *(const short8*)(qbase + fk);
  short8 qf1 = *(const short8*)(qbase + 32 + fk);
  f32x4 o[4] = {};
  float lrow = 0.0f;   // per-lane partial sum; reduced once after the loop

  // staging thread mapping
  int key0 = tid >> 3, c0 = tid & 7;                 // K: keys 0..31 (+32 second chunk)
  int kp = tid & 31, dg = tid >> 5, d0v = dg * 8;    // V: key pair 2kp,2kp+1, d rows d0v..d0v+7
  const u16* Kbase = Kg + (size_t)kvh * 2048 * 64;
  const u16* Vbase = Vg + (size_t)kvh * 2048 * 64;

  auto stage_load = [&](int kt2, short8& k0, short8& k1, short8& v0, short8& v1) {
    const u16* kb = Kbase + (size_t)kt2 * 64 * 64;
    k0 = *(const short8*)(kb + key0 * 64 + c0 * 8);
    k1 = *(const short8*)(kb + (32 + key0) * 64 + c0 * 8);
    const u16* vb = Vbase + (size_t)kt2 * 64 * 64 + (size_t)(2 * kp) * 64 + d0v;
    v0 = *(const short8*)vb;
    v1 = *(const short8*)(vb + 64);
  };
  auto stage_write = [&](short8 k0, short8 k1, short8 v0, short8 v1) {
    int offA = (key0 * 128 + c0 * 16) ^ ((key0 & 7) << 4);
    int offB = ((32 + key0) * 128 + c0 * 16) ^ ((key0 & 7) << 4);
    *(short8*)(KsB + offA) = k0;
    *(short8*)(KsB + offB) = k1;
#pragma unroll
    for (int j = 0; j < 8; ++j) {
      uint32_t pk = (uint32_t)(u16)v0[j] | ((uint32_t)(u16)v1[j] << 16);
      int d = d0v + j;
      int off = (d * 128 + kp * 4) ^ ((j & 7) << 4);   // d&7 == j
      *(uint32_t*)(VsB + off) = pk;
    }
  };

  short8 kA0, kA1, vA0, vA1, kB0, kB1, vB0, vB1;
  stage_load(0, kA0, kA1, vA0, vA1);

  uint32_t* Pw = &Ps[w][0];
  int swzr = (fr & 7) << 4;   // row-XOR for fragment reads
  int qrow = qt * 64 + w * 16 + fr;

  for (int kt = 0; kt <= qt; ++kt) {
    bool diag = (kt == qt);
    if ((kt & 1) == 0) stage_write(kA0, kA1, vA0, vA1);
    else               stage_write(kB0, kB1, vB0, vB1);
    __syncthreads();
    if (!diag) {   // prefetch next tile; lands under compute
      if ((kt & 1) == 0) stage_load(kt + 1, kB0, kB1, vB0, vB1);
      else               stage_load(kt + 1, kA0, kA1, vA0, vA1);
    }
    // S^T = K Q^T : lane (fr,hi) holds S[key=kt*64+g*16+hi*4+r][q-row=w*16+fr], log2 units
    f32x4 s4[4] = {};
    __builtin_amdgcn_s_setprio(1);
#pragma unroll
    for (int g = 0; g < 4; ++g) {
      int rb = (g * 16 + fr) * 128;
      short8 b0 = *(const short8*)(KsB + ((rb + hi * 16) ^ swzr));
      short8 b1 = *(const short8*)(KsB + ((rb + 64 + hi * 16) ^ swzr));
      s4[g] = __builtin_amdgcn_mfma_f32_16x16x32_bf16(b0, qf0, s4[g], 0, 0, 0);
      s4[g] = __builtin_amdgcn_mfma_f32_16x16x32_bf16(b1, qf1, s4[g], 0, 0, 0);
    }
    __builtin_amdgcn_s_setprio(0);
    // causal mask: only the diagonal tile crosses q==k
    if (diag) {
      int kbase = kt * 64 + hi * 4;
#pragma unroll
      for (int g = 0; g < 4; ++g)
#pragma unroll
        for (int r = 0; r < 4; ++r)
          if (kbase + g * 16 + r > qrow) s4[g][r] = -1e30f;
    }
    // P = exp2(S - mfix), lane-parallel; cvt_pk pack; per-lane partial l
#pragma unroll
    for (int g = 0; g < 4; ++g) {
      float p0 = exp2f(s4[g][0] - mfix);
      float p1 = exp2f(s4[g][1] - mfix);
      float p2 = exp2f(s4[g][2] - mfix);
      float p3 = exp2f(s4[g][3] - mfix);
      lrow += (p0 + p1) + (p2 + p3);
      uint2 pk = make_uint2(pack_bf16x2(p0, p1), pack_bf16x2(p2, p3));
      *(uint2*)&Pw[fr * 36 + g * 8 + hi * 2] = pk;   // b64
    }
    asm volatile("s_waitcnt lgkmcnt(0)" ::: "memory");  // P writes land (wave-local)
    // O += P V  (A-operand read back: u32 stride 36 -> b128 slot stride 9, conflict-free)
    short8 pa0 = *(const short8*)&Pw[fr * 36 + hi * 4];
    short8 pa1 = *(const short8*)&Pw[fr * 36 + 16 + hi * 4];
    __builtin_amdgcn_s_setprio(1);
#pragma unroll
    for (int g2 = 0; g2 < 4; ++g2) {
      int rb = (g2 * 16 + fr) * 128;
      short8 vb0 = *(const short8*)(VsB + ((rb + hi * 16) ^ swzr));
      short8 vb1 = *(const short8*)(VsB + ((rb + 64 + hi * 16) ^ swzr));
      o[g2] = __builtin_amdgcn_mfma_f32_16x16x32_bf16(pa0, vb0, o[g2], 0, 0, 0);
      o[g2] = __builtin_amdgcn_mfma_f32_16x16x32_bf16(pa1, vb1, o[g2], 0, 0, 0);
    }
    __builtin_amdgcn_s_setprio(0);
    __syncthreads();
  }
  // one l-reduction for the whole kernel
  float rtot = lrow;
  rtot += __shfl_xor(rtot, 16);
  rtot += __shfl_xor(rtot, 32);
#pragma unroll
  for (int r = 0; r < 4; ++r) {
    float li = __shfl(rtot, hi * 4 + r);
    float inv = 1.0f / li;
    size_t rowoff = (size_t)(qt * 64 + w * 16 + hi * 4 + r) * 2048 + h * 64;
#pragma unroll
    for (int g2 = 0; g2 < 4; ++g2)
      att[rowoff + g2 * 16 + fr] = f2bf(o[g2][r] * inv);
  }
}

extern "C" void kernel_launch(void* const* d_in, const int* in_sizes, int n_in,
                              void* d_out, int out_size, void* d_ws, size_t ws_size,
                              hipStream_t stream) {
  const float* x    = (const float*)d_in[0];
  const float* fc   = (const float*)d_in[1];
  const float* fs   = (const float*)d_in[2];
  // d_in[3] = mask (causal, regenerated in-kernel)
  const float* wq   = (const float*)d_in[4];
  const float* wq_b = (const float*)d_in[5];
  const float* wk   = (const float*)d_in[6];
  const float* wk_b = (const float*)d_in[7];
  const float* wv   = (const float*)d_in[8];
  const float* wv_b = (const float*)d_in[9];
  const float* wo   = (const float*)d_in[10];
  const float* wo_b = (const float*)d_in[11];
  const float* qn   = (const float*)d_in[12];
  const float* kn   = (const float*)d_in[13];
  float* out = (float*)d_out;

  char* ws = (char*)d_ws;
  u16*  xb    = (u16*)(ws);                          //  8 MB  x bf16 [2048][2048]
  u16*  wqkvT = (u16*)(ws + (size_t)(8  << 20));     // 12 MB  [3072][2048] bf16
  u16*  woT   = (u16*)(ws + (size_t)(20 << 20));     //  8 MB  [2048][2048] bf16
  float* qkv  = (float*)(ws + (size_t)(28 << 20));   // 24 MB  [2048][3072] f32
  u16*  Qg    = (u16*)(ws + (size_t)(52 << 20));     //  8 MB  [32][2048][64]
  u16*  Kg    = (u16*)(ws + (size_t)(60 << 20));     //  2 MB  [8][2048][64]
  u16*  Vg    = (u16*)(ws + (size_t)(62 << 20));     //  2 MB  [8][2048][64]
  u16*  att   = (u16*)(ws + (size_t)(64 << 20));     //  8 MB  [2048][2048]

  conv_bf16<<<4096, 256, 0, stream>>>(x, xb, 1048576);
  transpose_all<<<dim3(80, 32), 256, 0, stream>>>(wq, wk, wv, wo, wqkvT, woT);
  gemm_bt<<<32 * 24, 256, 0, stream>>>(xb, wqkvT, qkv, (const float*)nullptr, 2048, 3072, 2048);
  qkv_post<<<24576, 256, 0, stream>>>(qkv, wq_b, wk_b, wv_b, qn, kn, fc, fs, Qg, Kg, Vg);
  attn_kernel<<<1024, 256, 0, stream>>>(Qg, Kg, Vg, qn, kn, att);
  gemm_bt<<<32 * 16, 256, 0, stream>>>(att, woT, out, wo_b, 2048, 2048, 2048);
}

// Round 13
// 147.667 us; speedup vs baseline: 1.2775x; 1.0406x over previous
//
#include <hip/hip_runtime.h>
#include <hip/hip_bf16.h>
#include <cstdint>

typedef unsigned short u16;
typedef __attribute__((ext_vector_type(8))) short short8;   // 8 x bf16 fragment
typedef __attribute__((ext_vector_type(4))) float f32x4;

__device__ __forceinline__ u16 f2bf(float f) {
  union { float f; uint32_t u; } c; c.f = f;
  return (u16)((c.u + 0x7FFFu + ((c.u >> 16) & 1u)) >> 16);
}

__device__ __forceinline__ uint32_t pack_bf16x2(float a, float b) {
  union { __hip_bfloat162 h; uint32_t u; } c;
  c.h = __float22bfloat162_rn(make_float2(a, b));   // v_cvt_pk_bf16_f32
  return c.u;
}

// ---------- fp32 -> bf16 elementwise (4 per thread) ----------
__global__ __launch_bounds__(256) void conv_bf16(const float* __restrict__ in,
                                                 u16* __restrict__ out, int n4) {
  int i = blockIdx.x * 256 + threadIdx.x;
  if (i >= n4) return;
  float4 v = ((const float4*)in)[i];
  ((ushort4*)out)[i] = make_ushort4(f2bf(v.x), f2bf(v.y), f2bf(v.z), f2bf(v.w));
}

// ---------- all 4 weight transposes in one launch: [K][N] f32 -> [N][K] bf16 ----------
__global__ __launch_bounds__(256) void transpose_all(const float* __restrict__ wq,
                                                     const float* __restrict__ wk,
                                                     const float* __restrict__ wv,
                                                     const float* __restrict__ wo,
                                                     u16* __restrict__ wqkvT,
                                                     u16* __restrict__ woT) {
  __shared__ float tile[64][65];
  const int K = 2048;
  int bx = blockIdx.x;
  const float* in; u16* out; int N, nx;
  if (bx < 32)      { in = wq; out = wqkvT;                          N = 2048; nx = bx; }
  else if (bx < 40) { in = wk; out = wqkvT + (size_t)2048 * 2048;    N = 512;  nx = bx - 32; }
  else if (bx < 48) { in = wv; out = wqkvT + (size_t)2560 * 2048;    N = 512;  nx = bx - 40; }
  else              { in = wo; out = woT;                            N = 2048; nx = bx - 48; }
  int n0 = nx * 64, k0 = blockIdx.y * 64;
  int t = threadIdx.x;
  int a = t & 63, b4 = t >> 6;
#pragma unroll
  for (int j = 0; j < 16; ++j) {
    int kk = j * 4 + b4;
    tile[kk][a] = in[(size_t)(k0 + kk) * N + n0 + a];
  }
  __syncthreads();
#pragma unroll
  for (int j = 0; j < 16; ++j) {
    int nn = j * 4 + b4;
    out[(size_t)(n0 + nn) * K + k0 + a] = f2bf(tile[a][nn]);
  }
}

// ---------- bf16 GEMM: C[M][N] (f32,+bias) = A[M][K] * Bt[N][K]^T ----------
// 64x128 tile, BK=64, 2-phase dbuf, chunk-XOR swizzled LDS, XCD-swizzled grid.
__global__ __launch_bounds__(256, 3) void gemm_bt(const u16* __restrict__ A,
                                                  const u16* __restrict__ Bt,
                                                  float* __restrict__ C,
                                                  const float* __restrict__ bias,
                                                  int M, int N, int K) {
  __shared__ alignas(16) u16 As[2][64 * 64];     // [row][k], row chunk-swizzled
  __shared__ alignas(16) u16 Bs[2][128 * 64];
  int nb = N >> 7;
  int nwg = gridDim.x;
  int cpx = nwg >> 3;
  int bid = blockIdx.x;
  int swz = (bid & 7) * cpx + (bid >> 3);
  int m0 = (swz / nb) << 6;
  int n0 = (swz % nb) << 7;
  int tid = threadIdx.x;
  int w = tid >> 6, lane = tid & 63;
  int wr = w >> 1, wc = w & 1;
  int fr = lane & 15, hi = lane >> 4;
  int sw = fr & 7;                       // read-side swizzle (row&7 == fr&7)

  auto STAGE = [&](int buf, int kt) {
#pragma unroll
    for (int i = 0; i < 2; ++i) {
      int chunk = i * 256 + tid;
      int row = chunk >> 3, c = chunk & 7;
      const u16* ga = A + (size_t)(m0 + row) * K + kt + ((c ^ (row & 7)) << 3);
      u16* la = &As[buf][(size_t)(i * 256 + w * 64) * 8];
      __builtin_amdgcn_global_load_lds((const __attribute__((address_space(1))) void*)ga,
                                       (__attribute__((address_space(3))) void*)la, 16, 0, 0);
    }
#pragma unroll
    for (int i = 0; i < 4; ++i) {
      int chunk = i * 256 + tid;
      int row = chunk >> 3, c = chunk & 7;
      const u16* gb = Bt + (size_t)(n0 + row) * K + kt + ((c ^ (row & 7)) << 3);
      u16* lb = &Bs[buf][(size_t)(i * 256 + w * 64) * 8];
      __builtin_amdgcn_global_load_lds((const __attribute__((address_space(1))) void*)gb,
                                       (__attribute__((address_space(3))) void*)lb, 16, 0, 0);
    }
  };

  f32x4 acc[2][4] = {};
  STAGE(0, 0);
  __syncthreads();
  int cur = 0;
  int c0 = (hi ^ sw) << 3, c1 = ((4 + hi) ^ sw) << 3;   // k-chunk LDS offsets (u16)
  for (int kt = 0; kt < K; kt += 64) {
    if (kt + 64 < K) STAGE(cur ^ 1, kt + 64);
    short8 af[2][2], bf[4][2];
#pragma unroll
    for (int m = 0; m < 2; ++m) {
      int rb = (wr * 32 + m * 16 + fr) * 64;
      af[m][0] = *(const short8*)&As[cur][rb + c0];
      af[m][1] = *(const short8*)&As[cur][rb + c1];
    }
#pragma unroll
    for (int n = 0; n < 4; ++n) {
      int rb = (wc * 64 + n * 16 + fr) * 64;
      bf[n][0] = *(const short8*)&Bs[cur][rb + c0];
      bf[n][1] = *(const short8*)&Bs[cur][rb + c1];
    }
#pragma unroll
    for (int m = 0; m < 2; ++m)
#pragma unroll
      for (int n = 0; n < 4; ++n) {
        acc[m][n] = __builtin_amdgcn_mfma_f32_16x16x32_bf16(af[m][0], bf[n][0], acc[m][n], 0, 0, 0);
        acc[m][n] = __builtin_amdgcn_mfma_f32_16x16x32_bf16(af[m][1], bf[n][1], acc[m][n], 0, 0, 0);
      }
    __syncthreads();
    cur ^= 1;
  }
#pragma unroll
  for (int m = 0; m < 2; ++m) {
#pragma unroll
    for (int n = 0; n < 4; ++n) {
      int gcol = n0 + wc * 64 + n * 16 + fr;
      float bv = bias ? bias[gcol] : 0.0f;
#pragma unroll
      for (int r = 0; r < 4; ++r) {
        int grow = m0 + wr * 32 + m * 16 + hi * 4 + r;
        C[(size_t)grow * N + gcol] = acc[m][n][r] + bv;
      }
    }
  }
}

// ---------- QKV postprocess: bias + RMSNorm + RoPE + layout [head][t][64] bf16 ----------
__global__ __launch_bounds__(256) void qkv_post(const float* __restrict__ qkv,
    const float* __restrict__ wq_b, const float* __restrict__ wk_b, const float* __restrict__ wv_b,
    const float* __restrict__ qn_w, const float* __restrict__ kn_w,
    const float* __restrict__ fc, const float* __restrict__ fs,
    u16* __restrict__ Qg, u16* __restrict__ Kg, u16* __restrict__ Vg) {
  int gid = blockIdx.x * 256 + threadIdx.x;
  int wave = gid >> 6, d = gid & 63;
  int t = wave / 48, hh = wave % 48;
  float v;
  if (hh < 32)       v = qkv[(size_t)t * 3072 + hh * 64 + d] + wq_b[hh * 64 + d];
  else if (hh < 40)  v = qkv[(size_t)t * 3072 + 2048 + (hh - 32) * 64 + d] + wk_b[(hh - 32) * 64 + d];
  else               v = qkv[(size_t)t * 3072 + 2560 + (hh - 40) * 64 + d] + wv_b[(hh - 40) * 64 + d];
  if (hh < 40) {
    float sq = v * v;
#pragma unroll
    for (int off = 32; off >= 1; off >>= 1) sq += __shfl_xor(sq, off);
    float rr = rsqrtf(sq * (1.0f / 64.0f) + 1e-5f);
    float wn = (hh < 32) ? qn_w[d] * 0.18033688f : kn_w[d];   // Q: fold 0.125*log2(e)
    v = v * rr * wn;
    float part = __shfl_xor(v, 1);
    float c = fc[t * 32 + (d >> 1)];
    float s = fs[t * 32 + (d >> 1)];
    v = (d & 1) ? (part * s + v * c) : (v * c - part * s);
  }
  u16 bv = f2bf(v);
  if (hh < 32)       Qg[((size_t)hh * 2048 + t) * 64 + d] = bv;
  else if (hh < 40)  Kg[((size_t)(hh - 32) * 2048 + t) * 64 + d] = bv;
  else               Vg[((size_t)(hh - 40) * 2048 + t) * 64 + d] = bv;
}

// ---------- causal GQA flash attention (v8: single-sync dbuf LDS) ----------
__global__ __launch_bounds__(256, 3) void attn_kernel(const u16* __restrict__ Qg,
                                                      const u16* __restrict__ Kg,
                                                      const u16* __restrict__ Vg,
                                                      const float* __restrict__ qn_w,
                                                      const float* __restrict__ kn_w,
                                                      u16* __restrict__ att) {
  __shared__ alignas(16) u16 Ks[2][64 * 64];         // [key][d], XOR-swizzled rows
  __shared__ alignas(16) u16 Vs[2][64 * 64];         // [d][key], XOR-swizzled rows
  __shared__ alignas(16) uint32_t Ps[4][16 * 36];    // per-wave P: [q=fr][key-pair], stride 36

  // balanced remap: each CU's round-robin set {q0,15-q0,16+q0,31-q0} sums uniform
  int bid = blockIdx.x;
  int grp = bid >> 8, idx = bid & 255;
  int q0 = idx >> 5, h = idx & 31;
  int qt = (grp == 0) ? q0 : (grp == 1) ? 15 - q0 : (grp == 2) ? 16 + q0 : 31 - q0;
  int kvh = h >> 2;

  int tid = threadIdx.x, w = tid >> 6, lane = tid & 63;
  int fr = lane & 15, hi = lane >> 4, fk = hi * 8;

  // softmax upper bound: S_log2 <= 11.5416 * max|qn| * max|kn|
  float ba = fabsf(qn_w[lane]), bb = fabsf(kn_w[lane]);
#pragma unroll
  for (int off = 32; off >= 1; off >>= 1) {
    ba = fmaxf(ba, __shfl_xor(ba, off));
    bb = fmaxf(bb, __shfl_xor(bb, off));
  }
  float mfix = 11.5416222f * ba * bb;   // uniform softmax max (log2 domain)

  const u16* qbase = Qg + ((size_t)h * 2048 + qt * 64 + w * 16 + fr) * 64;
  short8 qf0 = *(const short8*)(qbase + fk);
  short8 qf1 = *(const short8*)(qbase + 32 + fk);
  f32x4 o[4] = {};
  float lrow = 0.0f;   // per-lane partial sum; reduced once after the loop

  // staging thread mapping
  int key0 = tid >> 3, c0 = tid & 7;                 // K: keys 0..31 (+32 second chunk)
  int kp = tid & 31, dg = tid >> 5, d0v = dg * 8;    // V: key pair 2kp,2kp+1, d rows d0v..d0v+7
  const u16* Kbase = Kg + (size_t)kvh * 2048 * 64;
  const u16* Vbase = Vg + (size_t)kvh * 2048 * 64;

  short8 k0r, k1r, v0r, v1r;   // single reg set: loaded at iter start, written at iter end
  auto stage_load = [&](int kt2) {
    const u16* kb = Kbase + (size_t)kt2 * 64 * 64;
    k0r = *(const short8*)(kb + key0 * 64 + c0 * 8);
    k1r = *(const short8*)(kb + (32 + key0) * 64 + c0 * 8);
    const u16* vb = Vbase + (size_t)kt2 * 64 * 64 + (size_t)(2 * kp) * 64 + d0v;
    v0r = *(const short8*)vb;
    v1r = *(const short8*)(vb + 64);
  };
  auto stage_write = [&](int buf) {
    char* KsB = (char*)&Ks[buf][0];
    char* VsB = (char*)&Vs[buf][0];
    int offA = (key0 * 128 + c0 * 16) ^ ((key0 & 7) << 4);
    int offB = ((32 + key0) * 128 + c0 * 16) ^ ((key0 & 7) << 4);
    *(short8*)(KsB + offA) = k0r;
    *(short8*)(KsB + offB) = k1r;
#pragma unroll
    for (int j = 0; j < 8; ++j) {
      uint32_t pk = (uint32_t)(u16)v0r[j] | ((uint32_t)(u16)v1r[j] << 16);
      int d = d0v + j;
      int off = (d * 128 + kp * 4) ^ ((j & 7) << 4);   // d&7 == j
      *(uint32_t*)(VsB + off) = pk;
    }
  };

  stage_load(0);
  stage_write(0);
  __syncthreads();

  uint32_t* Pw = &Ps[w][0];
  int swzr = (fr & 7) << 4;   // row-XOR for fragment reads
  int qrow = qt * 64 + w * 16 + fr;

  for (int kt = 0; kt <= qt; ++kt) {
    int buf = kt & 1;
    bool diag = (kt == qt);
    if (!diag) stage_load(kt + 1);   // global loads in flight under this iter's compute
    const char* KsB = (const char*)&Ks[buf][0];
    const char* VsB = (const char*)&Vs[buf][0];
    // S^T = K Q^T : lane (fr,hi) holds S[key=kt*64+g*16+hi*4+r][q-row=w*16+fr], log2 units
    f32x4 s4[4] = {};
    __builtin_amdgcn_s_setprio(1);
#pragma unroll
    for (int g = 0; g < 4; ++g) {
      int rb = (g * 16 + fr) * 128;
      short8 b0 = *(const short8*)(KsB + ((rb + hi * 16) ^ swzr));
      short8 b1 = *(const short8*)(KsB + ((rb + 64 + hi * 16) ^ swzr));
      s4[g] = __builtin_amdgcn_mfma_f32_16x16x32_bf16(b0, qf0, s4[g], 0, 0, 0);
      s4[g] = __builtin_amdgcn_mfma_f32_16x16x32_bf16(b1, qf1, s4[g], 0, 0, 0);
    }
    __builtin_amdgcn_s_setprio(0);
    // causal mask: only the diagonal tile crosses q==k
    if (diag) {
      int kbase = kt * 64 + hi * 4;
#pragma unroll
      for (int g = 0; g < 4; ++g)
#pragma unroll
        for (int r = 0; r < 4; ++r)
          if (kbase + g * 16 + r > qrow) s4[g][r] = -1e30f;
    }
    // P = exp2(S - mfix), lane-parallel; cvt_pk pack; per-lane partial l
#pragma unroll
    for (int g = 0; g < 4; ++g) {
      float p0 = exp2f(s4[g][0] - mfix);
      float p1 = exp2f(s4[g][1] - mfix);
      float p2 = exp2f(s4[g][2] - mfix);
      float p3 = exp2f(s4[g][3] - mfix);
      lrow += (p0 + p1) + (p2 + p3);
      uint2 pk = make_uint2(pack_bf16x2(p0, p1), pack_bf16x2(p2, p3));
      *(uint2*)&Pw[fr * 36 + g * 8 + hi * 2] = pk;   // b64
    }
    asm volatile("s_waitcnt lgkmcnt(0)" ::: "memory");  // P writes land (wave-local)
    // O += P V  (A-operand read back: u32 stride 36 -> b128 slot stride 9, conflict-free)
    short8 pa0 = *(const short8*)&Pw[fr * 36 + hi * 4];
    short8 pa1 = *(const short8*)&Pw[fr * 36 + 16 + hi * 4];
    __builtin_amdgcn_s_setprio(1);
#pragma unroll
    for (int g2 = 0; g2 < 4; ++g2) {
      int rb = (g2 * 16 + fr) * 128;
      short8 vb0 = *(const short8*)(VsB + ((rb + hi * 16) ^ swzr));
      short8 vb1 = *(const short8*)(VsB + ((rb + 64 + hi * 16) ^ swzr));
      o[g2] = __builtin_amdgcn_mfma_f32_16x16x32_bf16(pa0, vb0, o[g2], 0, 0, 0);
      o[g2] = __builtin_amdgcn_mfma_f32_16x16x32_bf16(pa1, vb1, o[g2], 0, 0, 0);
    }
    __builtin_amdgcn_s_setprio(0);
    if (!diag) stage_write(buf ^ 1);   // write next tile; sync below publishes it
    __syncthreads();                   // ONE barrier per iteration
  }
  // one l-reduction for the whole kernel
  float rtot = lrow;
  rtot += __shfl_xor(rtot, 16);
  rtot += __shfl_xor(rtot, 32);
#pragma unroll
  for (int r = 0; r < 4; ++r) {
    float li = __shfl(rtot, hi * 4 + r);
    float inv = 1.0f / li;
    size_t rowoff = (size_t)(qt * 64 + w * 16 + hi * 4 + r) * 2048 + h * 64;
#pragma unroll
    for (int g2 = 0; g2 < 4; ++g2)
      att[rowoff + g2 * 16 + fr] = f2bf(o[g2][r] * inv);
  }
}

extern "C" void kernel_launch(void* const* d_in, const int* in_sizes, int n_in,
                              void* d_out, int out_size, void* d_ws, size_t ws_size,
                              hipStream_t stream) {
  const float* x    = (const float*)d_in[0];
  const float* fc   = (const float*)d_in[1];
  const float* fs   = (const float*)d_in[2];
  // d_in[3] = mask (causal, regenerated in-kernel)
  const float* wq   = (const float*)d_in[4];
  const float* wq_b = (const float*)d_in[5];
  const float* wk   = (const float*)d_in[6];
  const float* wk_b = (const float*)d_in[7];
  const float* wv   = (const float*)d_in[8];
  const float* wv_b = (const float*)d_in[9];
  const float* wo   = (const float*)d_in[10];
  const float* wo_b = (const float*)d_in[11];
  const float* qn   = (const float*)d_in[12];
  const float* kn   = (const float*)d_in[13];
  float* out = (float*)d_out;

  char* ws = (char*)d_ws;
  u16*  xb    = (u16*)(ws);                          //  8 MB  x bf16 [2048][2048]
  u16*  wqkvT = (u16*)(ws + (size_t)(8  << 20));     // 12 MB  [3072][2048] bf16
  u16*  woT   = (u16*)(ws + (size_t)(20 << 20));     //  8 MB  [2048][2048] bf16
  float* qkv  = (float*)(ws + (size_t)(28 << 20));   // 24 MB  [2048][3072] f32
  u16*  Qg    = (u16*)(ws + (size_t)(52 << 20));     //  8 MB  [32][2048][64]
  u16*  Kg    = (u16*)(ws + (size_t)(60 << 20));     //  2 MB  [8][2048][64]
  u16*  Vg    = (u16*)(ws + (size_t)(62 << 20));     //  2 MB  [8][2048][64]
  u16*  att   = (u16*)(ws + (size_t)(64 << 20));     //  8 MB  [2048][2048]

  conv_bf16<<<4096, 256, 0, stream>>>(x, xb, 1048576);
  transpose_all<<<dim3(80, 32), 256, 0, stream>>>(wq, wk, wv, wo, wqkvT, woT);
  gemm_bt<<<32 * 24, 256, 0, stream>>>(xb, wqkvT, qkv, (const float*)nullptr, 2048, 3072, 2048);
  qkv_post<<<24576, 256, 0, stream>>>(qkv, wq_b, wk_b, wv_b, qn, kn, fc, fs, Qg, Kg, Vg);
  attn_kernel<<<1024, 256, 0, stream>>>(Qg, Kg, Vg, qn, kn, att);
  gemm_bt<<<32 * 16, 256, 0, stream>>>(att, woT, out, wo_b, 2048, 2048, 2048);
}

// Round 14
// 134.464 us; speedup vs baseline: 1.4029x; 1.0982x over previous
//
#include <hip/hip_runtime.h>
#include <hip/hip_bf16.h>
#include <cstdint>

typedef unsigned short u16;
typedef __attribute__((ext_vector_type(8))) short short8;   // 8 x bf16 fragment
typedef __attribute__((ext_vector_type(4))) float f32x4;

__device__ __forceinline__ u16 f2bf(float f) {
  union { float f; uint32_t u; } c; c.f = f;
  return (u16)((c.u + 0x7FFFu + ((c.u >> 16) & 1u)) >> 16);
}

__device__ __forceinline__ uint32_t pack_bf16x2(float a, float b) {
  union { __hip_bfloat162 h; uint32_t u; } c;
  c.h = __float22bfloat162_rn(make_float2(a, b));   // v_cvt_pk_bf16_f32
  return c.u;
}

// ---------- fp32 -> bf16 elementwise (4 per thread) ----------
__global__ __launch_bounds__(256) void conv_bf16(const float* __restrict__ in,
                                                 u16* __restrict__ out, int n4) {
  int i = blockIdx.x * 256 + threadIdx.x;
  if (i >= n4) return;
  float4 v = ((const float4*)in)[i];
  ((ushort4*)out)[i] = make_ushort4(f2bf(v.x), f2bf(v.y), f2bf(v.z), f2bf(v.w));
}

// ---------- all 4 weight transposes in one launch: [K][N] f32 -> [N][K] bf16 ----------
__global__ __launch_bounds__(256) void transpose_all(const float* __restrict__ wq,
                                                     const float* __restrict__ wk,
                                                     const float* __restrict__ wv,
                                                     const float* __restrict__ wo,
                                                     u16* __restrict__ wqkvT,
                                                     u16* __restrict__ woT) {
  __shared__ float tile[64][65];
  const int K = 2048;
  int bx = blockIdx.x;
  const float* in; u16* out; int N, nx;
  if (bx < 32)      { in = wq; out = wqkvT;                          N = 2048; nx = bx; }
  else if (bx < 40) { in = wk; out = wqkvT + (size_t)2048 * 2048;    N = 512;  nx = bx - 32; }
  else if (bx < 48) { in = wv; out = wqkvT + (size_t)2560 * 2048;    N = 512;  nx = bx - 40; }
  else              { in = wo; out = woT;                            N = 2048; nx = bx - 48; }
  int n0 = nx * 64, k0 = blockIdx.y * 64;
  int t = threadIdx.x;
  int a = t & 63, b4 = t >> 6;
#pragma unroll
  for (int j = 0; j < 16; ++j) {
    int kk = j * 4 + b4;
    tile[kk][a] = in[(size_t)(k0 + kk) * N + n0 + a];
  }
  __syncthreads();
#pragma unroll
  for (int j = 0; j < 16; ++j) {
    int nn = j * 4 + b4;
    out[(size_t)(n0 + nn) * K + k0 + a] = f2bf(tile[a][nn]);
  }
}

// ---------- QKV GEMM with fused bias+RMSNorm+RoPE+bf16-layout epilogue ----------
// C-tile 64x128, BK=64, 2-phase dbuf, chunk-XOR swizzle. Each wave's 64-col span is
// exactly one head (region boundaries 2048/2560 are 128-aligned).
__global__ __launch_bounds__(256, 3) void gemm_qkv(const u16* __restrict__ A,
                                                   const u16* __restrict__ Bt,
                                                   const float* __restrict__ wq_b,
                                                   const float* __restrict__ wk_b,
                                                   const float* __restrict__ wv_b,
                                                   const float* __restrict__ qn_w,
                                                   const float* __restrict__ kn_w,
                                                   const float* __restrict__ fc,
                                                   const float* __restrict__ fs,
                                                   u16* __restrict__ Qg,
                                                   u16* __restrict__ Kg,
                                                   u16* __restrict__ Vg) {
  const int K = 2048, nb = 24;
  __shared__ alignas(16) u16 As[2][64 * 64];
  __shared__ alignas(16) u16 Bs[2][128 * 64];
  int nwg = gridDim.x;
  int cpx = nwg >> 3;
  int bid = blockIdx.x;
  int swz = (bid & 7) * cpx + (bid >> 3);
  int m0 = (swz / nb) << 6;
  int tileN = swz % nb;
  int n0 = tileN << 7;
  int tid = threadIdx.x;
  int w = tid >> 6, lane = tid & 63;
  int wr = w >> 1, wc = w & 1;
  int fr = lane & 15, hi = lane >> 4;
  int sw = fr & 7;

  auto STAGE = [&](int buf, int kt) {
#pragma unroll
    for (int i = 0; i < 2; ++i) {
      int chunk = i * 256 + tid;
      int row = chunk >> 3, c = chunk & 7;
      const u16* ga = A + (size_t)(m0 + row) * K + kt + ((c ^ (row & 7)) << 3);
      u16* la = &As[buf][(size_t)(i * 256 + w * 64) * 8];
      __builtin_amdgcn_global_load_lds((const __attribute__((address_space(1))) void*)ga,
                                       (__attribute__((address_space(3))) void*)la, 16, 0, 0);
    }
#pragma unroll
    for (int i = 0; i < 4; ++i) {
      int chunk = i * 256 + tid;
      int row = chunk >> 3, c = chunk & 7;
      const u16* gb = Bt + (size_t)(n0 + row) * K + kt + ((c ^ (row & 7)) << 3);
      u16* lb = &Bs[buf][(size_t)(i * 256 + w * 64) * 8];
      __builtin_amdgcn_global_load_lds((const __attribute__((address_space(1))) void*)gb,
                                       (__attribute__((address_space(3))) void*)lb, 16, 0, 0);
    }
  };

  f32x4 acc[2][4] = {};
  STAGE(0, 0);
  __syncthreads();
  int cur = 0;
  int c0 = (hi ^ sw) << 3, c1 = ((4 + hi) ^ sw) << 3;
  for (int kt = 0; kt < K; kt += 64) {
    if (kt + 64 < K) STAGE(cur ^ 1, kt + 64);
    short8 af[2][2], bf[4][2];
#pragma unroll
    for (int m = 0; m < 2; ++m) {
      int rb = (wr * 32 + m * 16 + fr) * 64;
      af[m][0] = *(const short8*)&As[cur][rb + c0];
      af[m][1] = *(const short8*)&As[cur][rb + c1];
    }
#pragma unroll
    for (int n = 0; n < 4; ++n) {
      int rb = (wc * 64 + n * 16 + fr) * 64;
      bf[n][0] = *(const short8*)&Bs[cur][rb + c0];
      bf[n][1] = *(const short8*)&Bs[cur][rb + c1];
    }
#pragma unroll
    for (int m = 0; m < 2; ++m)
#pragma unroll
      for (int n = 0; n < 4; ++n) {
        acc[m][n] = __builtin_amdgcn_mfma_f32_16x16x32_bf16(af[m][0], bf[n][0], acc[m][n], 0, 0, 0);
        acc[m][n] = __builtin_amdgcn_mfma_f32_16x16x32_bf16(af[m][1], bf[n][1], acc[m][n], 0, 0, 0);
      }
    __syncthreads();
    cur ^= 1;
  }

  // ---- fused epilogue ----
  int fbase = n0 + wc * 64;        // global feature col of this wave's d=0
  const float* bias; const float* nw = qn_w; u16* outp;
  bool isV = false; float nscale = 1.0f;
  if (fbase < 2048)      { outp = Qg + (size_t)(fbase >> 6) * 2048 * 64;          bias = wq_b + fbase;          nw = qn_w; nscale = 0.18033688f; }
  else if (fbase < 2560) { outp = Kg + (size_t)((fbase - 2048) >> 6) * 2048 * 64; bias = wk_b + (fbase - 2048); nw = kn_w; }
  else                   { outp = Vg + (size_t)((fbase - 2560) >> 6) * 2048 * 64; bias = wv_b + (fbase - 2560); isV = true; }

  float bv[4], nwv[4];
#pragma unroll
  for (int n = 0; n < 4; ++n) {
    bv[n] = bias[n * 16 + fr];
    nwv[n] = isV ? 0.0f : nw[n * 16 + fr] * nscale;
  }
#pragma unroll
  for (int m = 0; m < 2; ++m) {
#pragma unroll
    for (int r = 0; r < 4; ++r) {
      int t = m0 + wr * 32 + m * 16 + hi * 4 + r;
      float v[4];
      float sq = 0.0f;
#pragma unroll
      for (int n = 0; n < 4; ++n) { v[n] = acc[m][n][r] + bv[n]; sq += v[n] * v[n]; }
      if (!isV) {
        sq += __shfl_xor(sq, 1); sq += __shfl_xor(sq, 2);
        sq += __shfl_xor(sq, 4); sq += __shfl_xor(sq, 8);
        float rr = rsqrtf(sq * (1.0f / 64.0f) + 1e-5f);
#pragma unroll
        for (int n = 0; n < 4; ++n) {
          float vn = v[n] * rr * nwv[n];
          float part = __shfl_xor(vn, 1);
          int dh = n * 16 + fr;
          float c = fc[t * 32 + (dh >> 1)];
          float s = fs[t * 32 + (dh >> 1)];
          v[n] = (dh & 1) ? (part * s + vn * c) : (vn * c - part * s);
        }
      }
#pragma unroll
      for (int n = 0; n < 4; ++n)
        outp[(size_t)t * 64 + n * 16 + fr] = f2bf(v[n]);
    }
  }
}

// ---------- bf16 GEMM: C[M][N] (f32,+bias) = A[M][K] * Bt[N][K]^T ----------
// 64x128 tile, BK=64, 2-phase dbuf, chunk-XOR swizzled LDS, XCD-swizzled grid.
__global__ __launch_bounds__(256, 3) void gemm_bt(const u16* __restrict__ A,
                                                  const u16* __restrict__ Bt,
                                                  float* __restrict__ C,
                                                  const float* __restrict__ bias,
                                                  int M, int N, int K) {
  __shared__ alignas(16) u16 As[2][64 * 64];
  __shared__ alignas(16) u16 Bs[2][128 * 64];
  int nb = N >> 7;
  int nwg = gridDim.x;
  int cpx = nwg >> 3;
  int bid = blockIdx.x;
  int swz = (bid & 7) * cpx + (bid >> 3);
  int m0 = (swz / nb) << 6;
  int n0 = (swz % nb) << 7;
  int tid = threadIdx.x;
  int w = tid >> 6, lane = tid & 63;
  int wr = w >> 1, wc = w & 1;
  int fr = lane & 15, hi = lane >> 4;
  int sw = fr & 7;

  auto STAGE = [&](int buf, int kt) {
#pragma unroll
    for (int i = 0; i < 2; ++i) {
      int chunk = i * 256 + tid;
      int row = chunk >> 3, c = chunk & 7;
      const u16* ga = A + (size_t)(m0 + row) * K + kt + ((c ^ (row & 7)) << 3);
      u16* la = &As[buf][(size_t)(i * 256 + w * 64) * 8];
      __builtin_amdgcn_global_load_lds((const __attribute__((address_space(1))) void*)ga,
                                       (__attribute__((address_space(3))) void*)la, 16, 0, 0);
    }
#pragma unroll
    for (int i = 0; i < 4; ++i) {
      int chunk = i * 256 + tid;
      int row = chunk >> 3, c = chunk & 7;
      const u16* gb = Bt + (size_t)(n0 + row) * K + kt + ((c ^ (row & 7)) << 3);
      u16* lb = &Bs[buf][(size_t)(i * 256 + w * 64) * 8];
      __builtin_amdgcn_global_load_lds((const __attribute__((address_space(1))) void*)gb,
                                       (__attribute__((address_space(3))) void*)lb, 16, 0, 0);
    }
  };

  f32x4 acc[2][4] = {};
  STAGE(0, 0);
  __syncthreads();
  int cur = 0;
  int c0 = (hi ^ sw) << 3, c1 = ((4 + hi) ^ sw) << 3;
  for (int kt = 0; kt < K; kt += 64) {
    if (kt + 64 < K) STAGE(cur ^ 1, kt + 64);
    short8 af[2][2], bf[4][2];
#pragma unroll
    for (int m = 0; m < 2; ++m) {
      int rb = (wr * 32 + m * 16 + fr) * 64;
      af[m][0] = *(const short8*)&As[cur][rb + c0];
      af[m][1] = *(const short8*)&As[cur][rb + c1];
    }
#pragma unroll
    for (int n = 0; n < 4; ++n) {
      int rb = (wc * 64 + n * 16 + fr) * 64;
      bf[n][0] = *(const short8*)&Bs[cur][rb + c0];
      bf[n][1] = *(const short8*)&Bs[cur][rb + c1];
    }
#pragma unroll
    for (int m = 0; m < 2; ++m)
#pragma unroll
      for (int n = 0; n < 4; ++n) {
        acc[m][n] = __builtin_amdgcn_mfma_f32_16x16x32_bf16(af[m][0], bf[n][0], acc[m][n], 0, 0, 0);
        acc[m][n] = __builtin_amdgcn_mfma_f32_16x16x32_bf16(af[m][1], bf[n][1], acc[m][n], 0, 0, 0);
      }
    __syncthreads();
    cur ^= 1;
  }
#pragma unroll
  for (int m = 0; m < 2; ++m) {
#pragma unroll
    for (int n = 0; n < 4; ++n) {
      int gcol = n0 + wc * 64 + n * 16 + fr;
      float bvx = bias ? bias[gcol] : 0.0f;
#pragma unroll
      for (int r = 0; r < 4; ++r) {
        int grow = m0 + wr * 32 + m * 16 + hi * 4 + r;
        C[(size_t)grow * N + gcol] = acc[m][n][r] + bvx;
      }
    }
  }
}

// ---------- causal GQA flash attention (v8: single-sync dbuf LDS) ----------
__global__ __launch_bounds__(256, 3) void attn_kernel(const u16* __restrict__ Qg,
                                                      const u16* __restrict__ Kg,
                                                      const u16* __restrict__ Vg,
                                                      const float* __restrict__ qn_w,
                                                      const float* __restrict__ kn_w,
                                                      u16* __restrict__ att) {
  __shared__ alignas(16) u16 Ks[2][64 * 64];         // [key][d], XOR-swizzled rows
  __shared__ alignas(16) u16 Vs[2][64 * 64];         // [d][key], XOR-swizzled rows
  __shared__ alignas(16) uint32_t Ps[4][16 * 36];    // per-wave P: [q=fr][key-pair], stride 36

  int bid = blockIdx.x;
  int grp = bid >> 8, idx = bid & 255;
  int q0 = idx >> 5, h = idx & 31;
  int qt = (grp == 0) ? q0 : (grp == 1) ? 15 - q0 : (grp == 2) ? 16 + q0 : 31 - q0;
  int kvh = h >> 2;

  int tid = threadIdx.x, w = tid >> 6, lane = tid & 63;
  int fr = lane & 15, hi = lane >> 4, fk = hi * 8;

  float ba = fabsf(qn_w[lane]), bb = fabsf(kn_w[lane]);
#pragma unroll
  for (int off = 32; off >= 1; off >>= 1) {
    ba = fmaxf(ba, __shfl_xor(ba, off));
    bb = fmaxf(bb, __shfl_xor(bb, off));
  }
  float mfix = 11.5416222f * ba * bb;   // uniform softmax max (log2 domain)

  const u16* qbase = Qg + ((size_t)h * 2048 + qt * 64 + w * 16 + fr) * 64;
  short8 qf0 = *(const short8*)(qbase + fk);
  short8 qf1 = *(const short8*)(qbase + 32 + fk);
  f32x4 o[4] = {};
  float lrow = 0.0f;

  int key0 = tid >> 3, c0 = tid & 7;
  int kp = tid & 31, dg = tid >> 5, d0v = dg * 8;
  const u16* Kbase = Kg + (size_t)kvh * 2048 * 64;
  const u16* Vbase = Vg + (size_t)kvh * 2048 * 64;

  short8 k0r, k1r, v0r, v1r;
  auto stage_load = [&](int kt2) {
    const u16* kb = Kbase + (size_t)kt2 * 64 * 64;
    k0r = *(const short8*)(kb + key0 * 64 + c0 * 8);
    k1r = *(const short8*)(kb + (32 + key0) * 64 + c0 * 8);
    const u16* vb = Vbase + (size_t)kt2 * 64 * 64 + (size_t)(2 * kp) * 64 + d0v;
    v0r = *(const short8*)vb;
    v1r = *(const short8*)(vb + 64);
  };
  auto stage_write = [&](int buf) {
    char* KsB = (char*)&Ks[buf][0];
    char* VsB = (char*)&Vs[buf][0];
    int offA = (key0 * 128 + c0 * 16) ^ ((key0 & 7) << 4);
    int offB = ((32 + key0) * 128 + c0 * 16) ^ ((key0 & 7) << 4);
    *(short8*)(KsB + offA) = k0r;
    *(short8*)(KsB + offB) = k1r;
#pragma unroll
    for (int j = 0; j < 8; ++j) {
      uint32_t pk = (uint32_t)(u16)v0r[j] | ((uint32_t)(u16)v1r[j] << 16);
      int d = d0v + j;
      int off = (d * 128 + kp * 4) ^ ((j & 7) << 4);
      *(uint32_t*)(VsB + off) = pk;
    }
  };

  stage_load(0);
  stage_write(0);
  __syncthreads();

  uint32_t* Pw = &Ps[w][0];
  int swzr = (fr & 7) << 4;
  int qrow = qt * 64 + w * 16 + fr;

  for (int kt = 0; kt <= qt; ++kt) {
    int buf = kt & 1;
    bool diag = (kt == qt);
    if (!diag) stage_load(kt + 1);
    const char* KsB = (const char*)&Ks[buf][0];
    const char* VsB = (const char*)&Vs[buf][0];
    f32x4 s4[4] = {};
    __builtin_amdgcn_s_setprio(1);
#pragma unroll
    for (int g = 0; g < 4; ++g) {
      int rb = (g * 16 + fr) * 128;
      short8 b0 = *(const short8*)(KsB + ((rb + hi * 16) ^ swzr));
      short8 b1 = *(const short8*)(KsB + ((rb + 64 + hi * 16) ^ swzr));
      s4[g] = __builtin_amdgcn_mfma_f32_16x16x32_bf16(b0, qf0, s4[g], 0, 0, 0);
      s4[g] = __builtin_amdgcn_mfma_f32_16x16x32_bf16(b1, qf1, s4[g], 0, 0, 0);
    }
    __builtin_amdgcn_s_setprio(0);
    if (diag) {
      int kbase = kt * 64 + hi * 4;
#pragma unroll
      for (int g = 0; g < 4; ++g)
#pragma unroll
        for (int r = 0; r < 4; ++r)
          if (kbase + g * 16 + r > qrow) s4[g][r] = -1e30f;
    }
#pragma unroll
    for (int g = 0; g < 4; ++g) {
      float p0 = exp2f(s4[g][0] - mfix);
      float p1 = exp2f(s4[g][1] - mfix);
      float p2 = exp2f(s4[g][2] - mfix);
      float p3 = exp2f(s4[g][3] - mfix);
      lrow += (p0 + p1) + (p2 + p3);
      uint2 pk = make_uint2(pack_bf16x2(p0, p1), pack_bf16x2(p2, p3));
      *(uint2*)&Pw[fr * 36 + g * 8 + hi * 2] = pk;
    }
    asm volatile("s_waitcnt lgkmcnt(0)" ::: "memory");
    short8 pa0 = *(const short8*)&Pw[fr * 36 + hi * 4];
    short8 pa1 = *(const short8*)&Pw[fr * 36 + 16 + hi * 4];
    __builtin_amdgcn_s_setprio(1);
#pragma unroll
    for (int g2 = 0; g2 < 4; ++g2) {
      int rb = (g2 * 16 + fr) * 128;
      short8 vb0 = *(const short8*)(VsB + ((rb + hi * 16) ^ swzr));
      short8 vb1 = *(const short8*)(VsB + ((rb + 64 + hi * 16) ^ swzr));
      o[g2] = __builtin_amdgcn_mfma_f32_16x16x32_bf16(pa0, vb0, o[g2], 0, 0, 0);
      o[g2] = __builtin_amdgcn_mfma_f32_16x16x32_bf16(pa1, vb1, o[g2], 0, 0, 0);
    }
    __builtin_amdgcn_s_setprio(0);
    if (!diag) stage_write(buf ^ 1);
    __syncthreads();
  }
  float rtot = lrow;
  rtot += __shfl_xor(rtot, 16);
  rtot += __shfl_xor(rtot, 32);
#pragma unroll
  for (int r = 0; r < 4; ++r) {
    float li = __shfl(rtot, hi * 4 + r);
    float inv = 1.0f / li;
    size_t rowoff = (size_t)(qt * 64 + w * 16 + hi * 4 + r) * 2048 + h * 64;
#pragma unroll
    for (int g2 = 0; g2 < 4; ++g2)
      att[rowoff + g2 * 16 + fr] = f2bf(o[g2][r] * inv);
  }
}

extern "C" void kernel_launch(void* const* d_in, const int* in_sizes, int n_in,
                              void* d_out, int out_size, void* d_ws, size_t ws_size,
                              hipStream_t stream) {
  const float* x    = (const float*)d_in[0];
  const float* fc   = (const float*)d_in[1];
  const float* fs   = (const float*)d_in[2];
  // d_in[3] = mask (causal, regenerated in-kernel)
  const float* wq   = (const float*)d_in[4];
  const float* wq_b = (const float*)d_in[5];
  const float* wk   = (const float*)d_in[6];
  const float* wk_b = (const float*)d_in[7];
  const float* wv   = (const float*)d_in[8];
  const float* wv_b = (const float*)d_in[9];
  const float* wo   = (const float*)d_in[10];
  const float* wo_b = (const float*)d_in[11];
  const float* qn   = (const float*)d_in[12];
  const float* kn   = (const float*)d_in[13];
  float* out = (float*)d_out;

  char* ws = (char*)d_ws;
  u16*  xb    = (u16*)(ws);                          //  8 MB  x bf16 [2048][2048]
  u16*  wqkvT = (u16*)(ws + (size_t)(8  << 20));     // 12 MB  [3072][2048] bf16
  u16*  woT   = (u16*)(ws + (size_t)(20 << 20));     //  8 MB  [2048][2048] bf16
  u16*  Qg    = (u16*)(ws + (size_t)(52 << 20));     //  8 MB  [32][2048][64]
  u16*  Kg    = (u16*)(ws + (size_t)(60 << 20));     //  2 MB  [8][2048][64]
  u16*  Vg    = (u16*)(ws + (size_t)(62 << 20));     //  2 MB  [8][2048][64]
  u16*  att   = (u16*)(ws + (size_t)(64 << 20));     //  8 MB  [2048][2048]

  conv_bf16<<<4096, 256, 0, stream>>>(x, xb, 1048576);
  transpose_all<<<dim3(80, 32), 256, 0, stream>>>(wq, wk, wv, wo, wqkvT, woT);
  gemm_qkv<<<32 * 24, 256, 0, stream>>>(xb, wqkvT, wq_b, wk_b, wv_b, qn, kn, fc, fs, Qg, Kg, Vg);
  attn_kernel<<<1024, 256, 0, stream>>>(Qg, Kg, Vg, qn, kn, att);
  gemm_bt<<<32 * 16, 256, 0, stream>>>(att, woT, out, wo_b, 2048, 2048, 2048);
}

// Round 15
// 133.978 us; speedup vs baseline: 1.4080x; 1.0036x over previous
//
#include <hip/hip_runtime.h>
#include <hip/hip_bf16.h>
#include <cstdint>

typedef unsigned short u16;
typedef __attribute__((ext_vector_type(8))) short short8;   // 8 x bf16 fragment
typedef __attribute__((ext_vector_type(4))) float f32x4;

__device__ __forceinline__ u16 f2bf(float f) {
  union { float f; uint32_t u; } c; c.f = f;
  return (u16)((c.u + 0x7FFFu + ((c.u >> 16) & 1u)) >> 16);
}

__device__ __forceinline__ uint32_t pack_bf16x2(float a, float b) {
  union { __hip_bfloat162 h; uint32_t u; } c;
  c.h = __float22bfloat162_rn(make_float2(a, b));   // v_cvt_pk_bf16_f32
  return c.u;
}

// ---------- fused prep: x->bf16 conversion + all 4 weight transposes ----------
__global__ __launch_bounds__(256) void prep_kernel(const float* __restrict__ x,
                                                   u16* __restrict__ xb,
                                                   const float* __restrict__ wq,
                                                   const float* __restrict__ wk,
                                                   const float* __restrict__ wv,
                                                   const float* __restrict__ wo,
                                                   u16* __restrict__ wqkvT,
                                                   u16* __restrict__ woT) {
  int id = blockIdx.x;
  if (id >= 2560) {   // conv part: 4096 blocks, 4 f32/thread
    int i = (id - 2560) * 256 + threadIdx.x;
    float4 v = ((const float4*)x)[i];
    ((ushort4*)xb)[i] = make_ushort4(f2bf(v.x), f2bf(v.y), f2bf(v.z), f2bf(v.w));
    return;
  }
  __shared__ float tile[64][65];
  const int K = 2048;
  int bx = id % 80, by = id / 80;
  const float* in; u16* out; int N, nx;
  if (bx < 32)      { in = wq; out = wqkvT;                          N = 2048; nx = bx; }
  else if (bx < 40) { in = wk; out = wqkvT + (size_t)2048 * 2048;    N = 512;  nx = bx - 32; }
  else if (bx < 48) { in = wv; out = wqkvT + (size_t)2560 * 2048;    N = 512;  nx = bx - 40; }
  else              { in = wo; out = woT;                            N = 2048; nx = bx - 48; }
  int n0 = nx * 64, k0 = by * 64;
  int t = threadIdx.x;
  int a = t & 63, b4 = t >> 6;
#pragma unroll
  for (int j = 0; j < 16; ++j) {
    int kk = j * 4 + b4;
    tile[kk][a] = in[(size_t)(k0 + kk) * N + n0 + a];
  }
  __syncthreads();
#pragma unroll
  for (int j = 0; j < 16; ++j) {
    int nn = j * 4 + b4;
    out[(size_t)(n0 + nn) * K + k0 + a] = f2bf(tile[a][nn]);
  }
}

// ---------- QKV GEMM with fused bias+RMSNorm+RoPE epilogue; V written transposed ----------
__global__ __launch_bounds__(256, 3) void gemm_qkv(const u16* __restrict__ A,
                                                   const u16* __restrict__ Bt,
                                                   const float* __restrict__ wq_b,
                                                   const float* __restrict__ wk_b,
                                                   const float* __restrict__ wv_b,
                                                   const float* __restrict__ qn_w,
                                                   const float* __restrict__ kn_w,
                                                   const float* __restrict__ fc,
                                                   const float* __restrict__ fs,
                                                   u16* __restrict__ Qg,
                                                   u16* __restrict__ Kg,
                                                   u16* __restrict__ Vgt) {
  const int K = 2048, nb = 24;
  __shared__ alignas(16) u16 As[2][64 * 64];
  __shared__ alignas(16) u16 Bs[2][128 * 64];
  int nwg = gridDim.x;
  int cpx = nwg >> 3;
  int bid = blockIdx.x;
  int swz = (bid & 7) * cpx + (bid >> 3);
  int m0 = (swz / nb) << 6;
  int n0 = (swz % nb) << 7;
  int tid = threadIdx.x;
  int w = tid >> 6, lane = tid & 63;
  int wr = w >> 1, wc = w & 1;
  int fr = lane & 15, hi = lane >> 4;
  int sw = fr & 7;

  auto STAGE = [&](int buf, int kt) {
#pragma unroll
    for (int i = 0; i < 2; ++i) {
      int chunk = i * 256 + tid;
      int row = chunk >> 3, c = chunk & 7;
      const u16* ga = A + (size_t)(m0 + row) * K + kt + ((c ^ (row & 7)) << 3);
      u16* la = &As[buf][(size_t)(i * 256 + w * 64) * 8];
      __builtin_amdgcn_global_load_lds((const __attribute__((address_space(1))) void*)ga,
                                       (__attribute__((address_space(3))) void*)la, 16, 0, 0);
    }
#pragma unroll
    for (int i = 0; i < 4; ++i) {
      int chunk = i * 256 + tid;
      int row = chunk >> 3, c = chunk & 7;
      const u16* gb = Bt + (size_t)(n0 + row) * K + kt + ((c ^ (row & 7)) << 3);
      u16* lb = &Bs[buf][(size_t)(i * 256 + w * 64) * 8];
      __builtin_amdgcn_global_load_lds((const __attribute__((address_space(1))) void*)gb,
                                       (__attribute__((address_space(3))) void*)lb, 16, 0, 0);
    }
  };

  f32x4 acc[2][4] = {};
  STAGE(0, 0);
  __syncthreads();
  int cur = 0;
  int c0 = (hi ^ sw) << 3, c1 = ((4 + hi) ^ sw) << 3;
  for (int kt = 0; kt < K; kt += 64) {
    if (kt + 64 < K) STAGE(cur ^ 1, kt + 64);
    short8 af[2][2], bf[4][2];
#pragma unroll
    for (int m = 0; m < 2; ++m) {
      int rb = (wr * 32 + m * 16 + fr) * 64;
      af[m][0] = *(const short8*)&As[cur][rb + c0];
      af[m][1] = *(const short8*)&As[cur][rb + c1];
    }
#pragma unroll
    for (int n = 0; n < 4; ++n) {
      int rb = (wc * 64 + n * 16 + fr) * 64;
      bf[n][0] = *(const short8*)&Bs[cur][rb + c0];
      bf[n][1] = *(const short8*)&Bs[cur][rb + c1];
    }
#pragma unroll
    for (int m = 0; m < 2; ++m)
#pragma unroll
      for (int n = 0; n < 4; ++n) {
        acc[m][n] = __builtin_amdgcn_mfma_f32_16x16x32_bf16(af[m][0], bf[n][0], acc[m][n], 0, 0, 0);
        acc[m][n] = __builtin_amdgcn_mfma_f32_16x16x32_bf16(af[m][1], bf[n][1], acc[m][n], 0, 0, 0);
      }
    __syncthreads();
    cur ^= 1;
  }

  // ---- fused epilogue ----
  int fbase = n0 + wc * 64;        // global feature col of this wave's d=0
  if (fbase >= 2560) {             // V: bias only, store TRANSPOSED Vgt[kvh*64+d][t]
    const float* bias = wv_b + (fbase - 2560);
    u16* vt = Vgt + (size_t)(fbase - 2560) * 2048;
    float bv[4];
#pragma unroll
    for (int n = 0; n < 4; ++n) bv[n] = bias[n * 16 + fr];
#pragma unroll
    for (int m = 0; m < 2; ++m)
#pragma unroll
      for (int r = 0; r < 4; ++r) {
        int t = m0 + wr * 32 + m * 16 + hi * 4 + r;
#pragma unroll
        for (int n = 0; n < 4; ++n)
          vt[(size_t)(n * 16 + fr) * 2048 + t] = f2bf(acc[m][n][r] + bv[n]);
      }
    return;
  }
  bool isQ = (fbase < 2048);
  const float* bias = isQ ? wq_b + fbase : wk_b + (fbase - 2048);
  const float* nw   = isQ ? qn_w : kn_w;
  float nscale      = isQ ? 0.18033688f : 1.0f;   // Q: fold 0.125*log2(e)
  u16* outp = isQ ? Qg + (size_t)(fbase >> 6) * 2048 * 64
                  : Kg + (size_t)((fbase - 2048) >> 6) * 2048 * 64;
  float bv[4], nwv[4];
#pragma unroll
  for (int n = 0; n < 4; ++n) {
    bv[n] = bias[n * 16 + fr];
    nwv[n] = nw[n * 16 + fr] * nscale;
  }
#pragma unroll
  for (int m = 0; m < 2; ++m) {
#pragma unroll
    for (int r = 0; r < 4; ++r) {
      int t = m0 + wr * 32 + m * 16 + hi * 4 + r;
      float v[4];
      float sq = 0.0f;
#pragma unroll
      for (int n = 0; n < 4; ++n) { v[n] = acc[m][n][r] + bv[n]; sq += v[n] * v[n]; }
      sq += __shfl_xor(sq, 1); sq += __shfl_xor(sq, 2);
      sq += __shfl_xor(sq, 4); sq += __shfl_xor(sq, 8);
      float rr = rsqrtf(sq * (1.0f / 64.0f) + 1e-5f);
#pragma unroll
      for (int n = 0; n < 4; ++n) {
        float vn = v[n] * rr * nwv[n];
        float part = __shfl_xor(vn, 1);
        int dh = n * 16 + fr;
        float c = fc[t * 32 + (dh >> 1)];
        float s = fs[t * 32 + (dh >> 1)];
        v[n] = (dh & 1) ? (part * s + vn * c) : (vn * c - part * s);
      }
#pragma unroll
      for (int n = 0; n < 4; ++n)
        outp[(size_t)t * 64 + n * 16 + fr] = f2bf(v[n]);
    }
  }
}

// ---------- bf16 GEMM: C[M][N] (f32,+bias) = A[M][K] * Bt[N][K]^T ----------
__global__ __launch_bounds__(256, 3) void gemm_bt(const u16* __restrict__ A,
                                                  const u16* __restrict__ Bt,
                                                  float* __restrict__ C,
                                                  const float* __restrict__ bias,
                                                  int M, int N, int K) {
  __shared__ alignas(16) u16 As[2][64 * 64];
  __shared__ alignas(16) u16 Bs[2][128 * 64];
  int nb = N >> 7;
  int nwg = gridDim.x;
  int cpx = nwg >> 3;
  int bid = blockIdx.x;
  int swz = (bid & 7) * cpx + (bid >> 3);
  int m0 = (swz / nb) << 6;
  int n0 = (swz % nb) << 7;
  int tid = threadIdx.x;
  int w = tid >> 6, lane = tid & 63;
  int wr = w >> 1, wc = w & 1;
  int fr = lane & 15, hi = lane >> 4;
  int sw = fr & 7;

  auto STAGE = [&](int buf, int kt) {
#pragma unroll
    for (int i = 0; i < 2; ++i) {
      int chunk = i * 256 + tid;
      int row = chunk >> 3, c = chunk & 7;
      const u16* ga = A + (size_t)(m0 + row) * K + kt + ((c ^ (row & 7)) << 3);
      u16* la = &As[buf][(size_t)(i * 256 + w * 64) * 8];
      __builtin_amdgcn_global_load_lds((const __attribute__((address_space(1))) void*)ga,
                                       (__attribute__((address_space(3))) void*)la, 16, 0, 0);
    }
#pragma unroll
    for (int i = 0; i < 4; ++i) {
      int chunk = i * 256 + tid;
      int row = chunk >> 3, c = chunk & 7;
      const u16* gb = Bt + (size_t)(n0 + row) * K + kt + ((c ^ (row & 7)) << 3);
      u16* lb = &Bs[buf][(size_t)(i * 256 + w * 64) * 8];
      __builtin_amdgcn_global_load_lds((const __attribute__((address_space(1))) void*)gb,
                                       (__attribute__((address_space(3))) void*)lb, 16, 0, 0);
    }
  };

  f32x4 acc[2][4] = {};
  STAGE(0, 0);
  __syncthreads();
  int cur = 0;
  int c0 = (hi ^ sw) << 3, c1 = ((4 + hi) ^ sw) << 3;
  for (int kt = 0; kt < K; kt += 64) {
    if (kt + 64 < K) STAGE(cur ^ 1, kt + 64);
    short8 af[2][2], bf[4][2];
#pragma unroll
    for (int m = 0; m < 2; ++m) {
      int rb = (wr * 32 + m * 16 + fr) * 64;
      af[m][0] = *(const short8*)&As[cur][rb + c0];
      af[m][1] = *(const short8*)&As[cur][rb + c1];
    }
#pragma unroll
    for (int n = 0; n < 4; ++n) {
      int rb = (wc * 64 + n * 16 + fr) * 64;
      bf[n][0] = *(const short8*)&Bs[cur][rb + c0];
      bf[n][1] = *(const short8*)&Bs[cur][rb + c1];
    }
#pragma unroll
    for (int m = 0; m < 2; ++m)
#pragma unroll
      for (int n = 0; n < 4; ++n) {
        acc[m][n] = __builtin_amdgcn_mfma_f32_16x16x32_bf16(af[m][0], bf[n][0], acc[m][n], 0, 0, 0);
        acc[m][n] = __builtin_amdgcn_mfma_f32_16x16x32_bf16(af[m][1], bf[n][1], acc[m][n], 0, 0, 0);
      }
    __syncthreads();
    cur ^= 1;
  }
#pragma unroll
  for (int m = 0; m < 2; ++m) {
#pragma unroll
    for (int n = 0; n < 4; ++n) {
      int gcol = n0 + wc * 64 + n * 16 + fr;
      float bvx = bias ? bias[gcol] : 0.0f;
#pragma unroll
      for (int r = 0; r < 4; ++r) {
        int grow = m0 + wr * 32 + m * 16 + hi * 4 + r;
        C[(size_t)grow * N + gcol] = acc[m][n][r] + bvx;
      }
    }
  }
}

// ---------- causal GQA flash attention (v9: K and V^T both via global_load_lds) ----------
__global__ __launch_bounds__(256, 3) void attn_kernel(const u16* __restrict__ Qg,
                                                      const u16* __restrict__ Kg,
                                                      const u16* __restrict__ Vgt,
                                                      const float* __restrict__ qn_w,
                                                      const float* __restrict__ kn_w,
                                                      u16* __restrict__ att) {
  __shared__ alignas(16) u16 Ks[2][64 * 64];         // [key][d], src-swizzled
  __shared__ alignas(16) u16 Vs[2][64 * 64];         // [d][key], src-swizzled
  __shared__ alignas(16) uint32_t Ps[4][16 * 36];    // per-wave P: [q=fr][key-pair], stride 36

  int bid = blockIdx.x;
  int grp = bid >> 8, idx = bid & 255;
  int q0 = idx >> 5, h = idx & 31;
  int qt = (grp == 0) ? q0 : (grp == 1) ? 15 - q0 : (grp == 2) ? 16 + q0 : 31 - q0;
  int kvh = h >> 2;

  int tid = threadIdx.x, w = tid >> 6, lane = tid & 63;
  int fr = lane & 15, hi = lane >> 4, fk = hi * 8;

  float ba = fabsf(qn_w[lane]), bb = fabsf(kn_w[lane]);
#pragma unroll
  for (int off = 32; off >= 1; off >>= 1) {
    ba = fmaxf(ba, __shfl_xor(ba, off));
    bb = fmaxf(bb, __shfl_xor(bb, off));
  }
  float mfix = 11.5416222f * ba * bb;   // uniform softmax max (log2 domain)

  const u16* qbase = Qg + ((size_t)h * 2048 + qt * 64 + w * 16 + fr) * 64;
  short8 qf0 = *(const short8*)(qbase + fk);
  short8 qf1 = *(const short8*)(qbase + 32 + fk);
  f32x4 o[4] = {};
  float lrow = 0.0f;

  const u16* Kbase = Kg + (size_t)kvh * 2048 * 64;
  const u16* Vtbase = Vgt + (size_t)kvh * 64 * 2048;
  int row0 = tid >> 3, cc = tid & 7;   // chunk mapping: 2 chunks/thread per tile

  auto stage = [&](int buf, int kt) {
#pragma unroll
    for (int i = 0; i < 2; ++i) {
      int row = i * 32 + row0;         // K: key row; V: d row
      const u16* srcK = Kbase + ((size_t)(kt * 64 + row)) * 64 + ((cc ^ (row & 7)) << 3);
      u16* dstK = &Ks[buf][(size_t)(i * 256 + w * 64) * 8];
      __builtin_amdgcn_global_load_lds((const __attribute__((address_space(1))) void*)srcK,
                                       (__attribute__((address_space(3))) void*)dstK, 16, 0, 0);
      const u16* srcV = Vtbase + (size_t)row * 2048 + kt * 64 + ((cc ^ (row & 7)) << 3);
      u16* dstV = &Vs[buf][(size_t)(i * 256 + w * 64) * 8];
      __builtin_amdgcn_global_load_lds((const __attribute__((address_space(1))) void*)srcV,
                                       (__attribute__((address_space(3))) void*)dstV, 16, 0, 0);
    }
  };

  stage(0, 0);
  __syncthreads();

  uint32_t* Pw = &Ps[w][0];
  int swzr = (fr & 7) << 4;
  int qrow = qt * 64 + w * 16 + fr;

  for (int kt = 0; kt <= qt; ++kt) {
    int buf = kt & 1;
    bool diag = (kt == qt);
    if (!diag) stage(buf ^ 1, kt + 1);   // loads in flight under this iter's compute
    const char* KsB = (const char*)&Ks[buf][0];
    const char* VsB = (const char*)&Vs[buf][0];
    f32x4 s4[4] = {};
    __builtin_amdgcn_s_setprio(1);
#pragma unroll
    for (int g = 0; g < 4; ++g) {
      int rb = (g * 16 + fr) * 128;
      short8 b0 = *(const short8*)(KsB + ((rb + hi * 16) ^ swzr));
      short8 b1 = *(const short8*)(KsB + ((rb + 64 + hi * 16) ^ swzr));
      s4[g] = __builtin_amdgcn_mfma_f32_16x16x32_bf16(b0, qf0, s4[g], 0, 0, 0);
      s4[g] = __builtin_amdgcn_mfma_f32_16x16x32_bf16(b1, qf1, s4[g], 0, 0, 0);
    }
    __builtin_amdgcn_s_setprio(0);
    if (diag) {
      int kbase = kt * 64 + hi * 4;
#pragma unroll
      for (int g = 0; g < 4; ++g)
#pragma unroll
        for (int r = 0; r < 4; ++r)
          if (kbase + g * 16 + r > qrow) s4[g][r] = -1e30f;
    }
#pragma unroll
    for (int g = 0; g < 4; ++g) {
      float p0 = exp2f(s4[g][0] - mfix);
      float p1 = exp2f(s4[g][1] - mfix);
      float p2 = exp2f(s4[g][2] - mfix);
      float p3 = exp2f(s4[g][3] - mfix);
      lrow += (p0 + p1) + (p2 + p3);
      uint2 pk = make_uint2(pack_bf16x2(p0, p1), pack_bf16x2(p2, p3));
      *(uint2*)&Pw[fr * 36 + g * 8 + hi * 2] = pk;
    }
    asm volatile("s_waitcnt lgkmcnt(0)" ::: "memory");
    short8 pa0 = *(const short8*)&Pw[fr * 36 + hi * 4];
    short8 pa1 = *(const short8*)&Pw[fr * 36 + 16 + hi * 4];
    __builtin_amdgcn_s_setprio(1);
#pragma unroll
    for (int g2 = 0; g2 < 4; ++g2) {
      int rb = (g2 * 16 + fr) * 128;
      short8 vb0 = *(const short8*)(VsB + ((rb + hi * 16) ^ swzr));
      short8 vb1 = *(const short8*)(VsB + ((rb + 64 + hi * 16) ^ swzr));
      o[g2] = __builtin_amdgcn_mfma_f32_16x16x32_bf16(pa0, vb0, o[g2], 0, 0, 0);
      o[g2] = __builtin_amdgcn_mfma_f32_16x16x32_bf16(pa1, vb1, o[g2], 0, 0, 0);
    }
    __builtin_amdgcn_s_setprio(0);
    __syncthreads();   // publishes buf^1 (vmcnt drain) + closes WAR on buf
  }
  float rtot = lrow;
  rtot += __shfl_xor(rtot, 16);
  rtot += __shfl_xor(rtot, 32);
#pragma unroll
  for (int r = 0; r < 4; ++r) {
    float li = __shfl(rtot, hi * 4 + r);
    float inv = 1.0f / li;
    size_t rowoff = (size_t)(qt * 64 + w * 16 + hi * 4 + r) * 2048 + h * 64;
#pragma unroll
    for (int g2 = 0; g2 < 4; ++g2)
      att[rowoff + g2 * 16 + fr] = f2bf(o[g2][r] * inv);
  }
}

extern "C" void kernel_launch(void* const* d_in, const int* in_sizes, int n_in,
                              void* d_out, int out_size, void* d_ws, size_t ws_size,
                              hipStream_t stream) {
  const float* x    = (const float*)d_in[0];
  const float* fc   = (const float*)d_in[1];
  const float* fs   = (const float*)d_in[2];
  // d_in[3] = mask (causal, regenerated in-kernel)
  const float* wq   = (const float*)d_in[4];
  const float* wq_b = (const float*)d_in[5];
  const float* wk   = (const float*)d_in[6];
  const float* wk_b = (const float*)d_in[7];
  const float* wv   = (const float*)d_in[8];
  const float* wv_b = (const float*)d_in[9];
  const float* wo   = (const float*)d_in[10];
  const float* wo_b = (const float*)d_in[11];
  const float* qn   = (const float*)d_in[12];
  const float* kn   = (const float*)d_in[13];
  float* out = (float*)d_out;

  char* ws = (char*)d_ws;
  u16*  xb    = (u16*)(ws);                          //  8 MB  x bf16 [2048][2048]
  u16*  wqkvT = (u16*)(ws + (size_t)(8  << 20));     // 12 MB  [3072][2048] bf16
  u16*  woT   = (u16*)(ws + (size_t)(20 << 20));     //  8 MB  [2048][2048] bf16
  u16*  Qg    = (u16*)(ws + (size_t)(52 << 20));     //  8 MB  [32][2048][64]
  u16*  Kg    = (u16*)(ws + (size_t)(60 << 20));     //  2 MB  [8][2048][64]
  u16*  Vgt   = (u16*)(ws + (size_t)(62 << 20));     //  2 MB  [8][64][2048] (V transposed)
  u16*  att   = (u16*)(ws + (size_t)(64 << 20));     //  8 MB  [2048][2048]

  prep_kernel<<<6656, 256, 0, stream>>>(x, xb, wq, wk, wv, wo, wqkvT, woT);
  gemm_qkv<<<32 * 24, 256, 0, stream>>>(xb, wqkvT, wq_b, wk_b, wv_b, qn, kn, fc, fs, Qg, Kg, Vgt);
  attn_kernel<<<1024, 256, 0, stream>>>(Qg, Kg, Vgt, qn, kn, att);
  gemm_bt<<<32 * 16, 256, 0, stream>>>(att, woT, out, wo_b, 2048, 2048, 2048);
}